// Round 3
// baseline (384.403 us; speedup 1.0000x reference)
//
#include <hip/hip_runtime.h>
#include <stdint.h>

// ---------------------------------------------------------------------------
// MultiHeadAttention: B=8 S=1024 QKV=1024 H=16 E=64 OUT=1024.
// fp32 in / fp32 out, bf16 MFMA internals, fp32 accum.
// R10: GEMM 2-phase double-buffer + flash K via gld16+XOR-swizzle + merges.
//  - gemm_core: LDS [2][128x64] per operand (64 KB). Per iter: issue next
//    tile's 8 global_load_lds FIRST, then ds_read+MFMA current, then one
//    barrier (compiler's vmcnt(0) drain lands after ~500cy of compute ->
//    load latency hidden inside the block; we only have 2 blocks/CU so
//    inter-block overlap can't hide it, unlike m97's 3/CU).
//  - flash: K staged via gld16 into linear Ks[64][64] with granule XOR
//    swizzle (src granule = (lane&7)^(lane>>3); read granule = g^(row&7)).
//    Removes K's VGPR round-trip + ds_writes. V/P/Q paths unchanged.
//  - prep_wt x3 merged into one 768-block launch; Wo cvt folded into the
//    q/k cvt (grid 4352).
// flash MFMA maps (HW-verified m89/m91):
//   A[m=lane&15][k=quad*8+j], B[k=quad*8+j][n=lane&15], D[row=quad*4+r][col]
// ws: [Qp 16][Kp 16][Vp 16][WqT 2|WkT 2|WvT 2|WoB 2] = 56 MB.
// d_out doubles as bf16 scratch (q~ at 0, k~ at 16MB; v~ reuses slot 0).
// ---------------------------------------------------------------------------

typedef __bf16 bf16x8 __attribute__((ext_vector_type(8)));
typedef float f32x4 __attribute__((ext_vector_type(4)));

typedef __attribute__((address_space(3))) uint32_t lds_u32;
typedef const __attribute__((address_space(1))) uint32_t glb_u32;

__device__ __forceinline__ ushort f2bf(float f) {
  uint32_t x = __float_as_uint(f);
  x += 0x7fff + ((x >> 16) & 1);  // RNE
  return (ushort)(x >> 16);
}
__device__ __forceinline__ bf16x8 ld8(const ushort* p) {
  union { uint4 u; bf16x8 b; } c;
  c.u = *reinterpret_cast<const uint4*>(p);
  return c.b;
}
__device__ __forceinline__ void cvt16(const float* __restrict__ src,
                                      ushort* __restrict__ dst) {
  union { uint4 u[2]; ushort s[16]; } o;
#pragma unroll
  for (int i = 0; i < 4; ++i) {
    const float4 f = reinterpret_cast<const float4*>(src)[i];
    o.s[4 * i + 0] = f2bf(f.x);
    o.s[4 * i + 1] = f2bf(f.y);
    o.s[4 * i + 2] = f2bf(f.z);
    o.s[4 * i + 3] = f2bf(f.w);
  }
  reinterpret_cast<uint4*>(dst)[0] = o.u[0];
  reinterpret_cast<uint4*>(dst)[1] = o.u[1];
}

// global->LDS DMA, 16B/lane. LDS dest wave-uniform base + lane*16 (m104/m108).
__device__ __forceinline__ void gld16(const ushort* g, ushort* l) {
  __builtin_amdgcn_global_load_lds((glb_u32*)g, (lds_u32*)l, 16, 0, 0);
}

// --------------------------------------------------------------------------
// W[16][1024][64] fp32 -> WT[1024][1024] bf16 (WT[n=h*64+e][k]).
// 3 weights in one launch: grid 768 (bid>>8 selects W). 256 thr.
// --------------------------------------------------------------------------
__global__ __launch_bounds__(256) void prep_wt3(
    const float* __restrict__ W0, const float* __restrict__ W1,
    const float* __restrict__ W2, ushort* __restrict__ T0,
    ushort* __restrict__ T1, ushort* __restrict__ T2) {
  __shared__ __align__(16) ushort tile[64 * 72];
  const int sel = blockIdx.x >> 8;
  const float* W = sel == 0 ? W0 : sel == 1 ? W1 : W2;
  ushort* WT = sel == 0 ? T0 : sel == 1 ? T1 : T2;
  const int bid = blockIdx.x & 255;
  const int h = bid >> 4;
  const int kt = bid & 15;
  const int t = threadIdx.x;
  const int row = t >> 2;
  const int ch = (t & 3) * 16;
  cvt16(W + ((size_t)h * 1024 + kt * 64 + row) * 64 + ch, &tile[row * 72 + ch]);
  __syncthreads();
  const int e = t >> 2;
  const int kc = (t & 3) * 16;
  ushort vals[16];
#pragma unroll
  for (int j = 0; j < 16; ++j) vals[j] = tile[(kc + j) * 72 + e];
  ushort* dst = WT + (size_t)(h * 64 + e) * 1024 + kt * 64 + kc;
  reinterpret_cast<uint4*>(dst)[0] = *reinterpret_cast<uint4*>(&vals[0]);
  reinterpret_cast<uint4*>(dst)[1] = *reinterpret_cast<uint4*>(&vals[8]);
}

// fp32 -> bf16 elementwise, 16 elems/thread. grid = elems/4096.
__global__ __launch_bounds__(256) void cvt_wo(const float* __restrict__ src,
                                              ushort* __restrict__ dst) {
  const int i = (blockIdx.x * 256 + threadIdx.x) * 16;
  cvt16(src + i, dst + i);
}

// q (8M) + k (8M) + Wo (1M) in one launch. grid 4352.
__global__ __launch_bounds__(256) void cvt3(const float* __restrict__ s0,
                                            ushort* __restrict__ d0,
                                            const float* __restrict__ s1,
                                            ushort* __restrict__ d1,
                                            const float* __restrict__ s2,
                                            ushort* __restrict__ d2) {
  int b = blockIdx.x;
  const float* s;
  ushort* d;
  if (b < 2048) { s = s0; d = d0; }
  else if (b < 4096) { s = s1; d = d1; b -= 2048; }
  else { s = s2; d = d2; b -= 4096; }
  const int i = (b * 256 + threadIdx.x) * 16;
  cvt16(s + i, d + i);
}

// --------------------------------------------------------------------------
// GEMM core: C[8192][1024] = A bf16 @ Bt bf16 ^T (*oscale, + bias).
// 128x128 tile, BK=64, 4 waves 2x2, linear LDS, gld16 staging, 2-phase
// double-buffer: stage(next) -> compute(cur) -> barrier. 64 KB LDS.
// --------------------------------------------------------------------------
__device__ __forceinline__ void stage_ab(const ushort* a_src,
                                         const ushort* b_src, ushort* as,
                                         ushort* bs, int w, int k0) {
#pragma unroll
  for (int c = 0; c < 4; ++c) {
    gld16(a_src + (size_t)c * 32 * 1024 + k0, as + (w * 8 + c * 32) * 64);
    gld16(b_src + (size_t)c * 32 * 1024 + k0, bs + (w * 8 + c * 32) * 64);
  }
}

template <bool F32OUT>
__device__ __forceinline__ void gemm_core(const ushort* __restrict__ A,
                                          const ushort* __restrict__ Bt,
                                          const float* __restrict__ bias,
                                          void* __restrict__ Cv, float oscale,
                                          int bx, int by) {
  __shared__ __align__(16) ushort As[2][128 * 64];
  __shared__ __align__(16) ushort Bs[2][128 * 64];
  const int n0 = bx * 128;
  const int m0 = by * 128;
  const int t = threadIdx.x;
  const int lane = t & 63;
  const int w = t >> 6;
  const int wm = w >> 1, wn = w & 1;
  const int col = lane & 15;
  const int quad = lane >> 4;
  const int gr = lane >> 3;        // 0..7
  const int gc = (lane & 7) * 8;   // ushort col 0..56

  f32x4 acc[4][4];
#pragma unroll
  for (int i = 0; i < 4; ++i)
#pragma unroll
    for (int j = 0; j < 4; ++j) acc[i][j] = (f32x4){0.f, 0.f, 0.f, 0.f};

  const ushort* a_src = A + (size_t)(m0 + w * 8 + gr) * 1024 + gc;
  const ushort* b_src = Bt + (size_t)(n0 + w * 8 + gr) * 1024 + gc;

  stage_ab(a_src, b_src, As[0], Bs[0], w, 0);
  __syncthreads();

  int cur = 0;
  for (int it = 0; it < 16; ++it) {
    if (it < 15)
      stage_ab(a_src, b_src, As[cur ^ 1], Bs[cur ^ 1], w, (it + 1) * 64);
    const ushort* asb = As[cur];
    const ushort* bsb = Bs[cur];
#pragma unroll
    for (int half = 0; half < 2; ++half) {
      bf16x8 af[4], bfr[4];
#pragma unroll
      for (int i = 0; i < 4; ++i)
        af[i] = ld8(&asb[(wm * 64 + i * 16 + col) * 64 + half * 32 + quad * 8]);
#pragma unroll
      for (int j = 0; j < 4; ++j)
        bfr[j] = ld8(&bsb[(wn * 64 + j * 16 + col) * 64 + half * 32 + quad * 8]);
#pragma unroll
      for (int i = 0; i < 4; ++i)
#pragma unroll
        for (int j = 0; j < 4; ++j)
          acc[i][j] = __builtin_amdgcn_mfma_f32_16x16x32_bf16(af[i], bfr[j],
                                                              acc[i][j], 0, 0, 0);
    }
    __syncthreads();
    cur ^= 1;
  }

#pragma unroll
  for (int i = 0; i < 4; ++i)
#pragma unroll
    for (int j = 0; j < 4; ++j) {
      const int n = n0 + wn * 64 + j * 16 + col;
      float bv = 0.f;
      if (F32OUT) bv = bias[n];
#pragma unroll
      for (int r = 0; r < 4; ++r) {
        const int m = m0 + wm * 64 + i * 16 + quad * 4 + r;
        if (F32OUT)
          reinterpret_cast<float*>(Cv)[(size_t)m * 1024 + n] = acc[i][j][r] + bv;
        else
          reinterpret_cast<ushort*>(Cv)[(size_t)m * 1024 + n] =
              f2bf(acc[i][j][r] * oscale);
      }
    }
}

template <bool F32OUT>
__global__ __launch_bounds__(256) void gemm_bb(const ushort* __restrict__ A,
                                               const ushort* __restrict__ Bt,
                                               const float* __restrict__ bias,
                                               void* __restrict__ Cv,
                                               float oscale) {
  gemm_core<F32OUT>(A, Bt, bias, Cv, oscale, blockIdx.x, blockIdx.y);
}

// Q and K projections in one launch: grid dim3(8, 64, 2) -> 1024 blocks.
__global__ __launch_bounds__(256) void gemm_proj2(
    const ushort* __restrict__ A0, const ushort* __restrict__ B0,
    ushort* __restrict__ C0, float s0, const ushort* __restrict__ A1,
    const ushort* __restrict__ B1, ushort* __restrict__ C1, float s1) {
  if (blockIdx.z == 0)
    gemm_core<false>(A0, B0, nullptr, C0, s0, blockIdx.x, blockIdx.y);
  else
    gemm_core<false>(A1, B1, nullptr, C1, s1, blockIdx.x, blockIdx.y);
}

// --------------------------------------------------------------------------
// Flash attention, 128-row q-tiles. Q,K,V,O bf16 [8192][1024], O aliases Q.
// Q is PRE-SCALED by 1/sqrt(1024) (folded into the Q projection).
// grid 1024: pair=bid&127 -> (b,h), qt=bid>>7. block 256 (4 waves); wave w
// owns q-rows w*32..w*32+31. Swapped QK^T (lane-local softmax rows).
// K staged via gld16 into LINEAR Ks[64][64] with granule XOR swizzle:
//   store: lane fetches global granule (lane&7)^(lane>>3) of its row
//   read:  granule g of row R lives at LDS granule g^(R&7)
// -> conflict-free-ish reads without padding; staging is pure DMA.
// Barriers: 2/kt. LDS 35 KB.
// --------------------------------------------------------------------------
__global__ __launch_bounds__(256) void flash_attn(const ushort* __restrict__ Q,
                                                  const ushort* __restrict__ K,
                                                  const ushort* __restrict__ V,
                                                  ushort* __restrict__ O) {
  __shared__ __align__(16) ushort QP[128 * 72];
  __shared__ __align__(16) ushort Ks[64 * 64];
  __shared__ __align__(16) ushort Vt[64 * 72];
  const int pair = blockIdx.x & 127;
  const int b = pair >> 4;
  const int h = pair & 15;
  const int qt = blockIdx.x >> 7;
  const int t = threadIdx.x;
  const int lane = t & 63;
  const int w = t >> 6;
  const int col = lane & 15;
  const int quad = lane >> 4;

  const size_t base = (size_t)b * 1024 * 1024 + h * 64;
  const int qrow0 = qt * 128;

  // stage Q (128 x 64): 32 ushorts per thread
  {
    const int row = t >> 1;
    const int c0 = (t & 1) * 32;
    const ushort* src = Q + base + (size_t)(qrow0 + row) * 1024 + c0;
    uint4 v0 = reinterpret_cast<const uint4*>(src)[0];
    uint4 v1 = reinterpret_cast<const uint4*>(src)[1];
    uint4 v2 = reinterpret_cast<const uint4*>(src)[2];
    uint4 v3 = reinterpret_cast<const uint4*>(src)[3];
    reinterpret_cast<uint4*>(&QP[row * 72 + c0])[0] = v0;
    reinterpret_cast<uint4*>(&QP[row * 72 + c0])[1] = v1;
    reinterpret_cast<uint4*>(&QP[row * 72 + c0])[2] = v2;
    reinterpret_cast<uint4*>(&QP[row * 72 + c0])[3] = v3;
  }
  __syncthreads();
  bf16x8 qa[2][2];
#pragma unroll
  for (int g = 0; g < 2; ++g)
#pragma unroll
    for (int half = 0; half < 2; ++half)
      qa[g][half] =
          ld8(&QP[(w * 32 + g * 16 + col) * 72 + half * 32 + quad * 8]);
  // qa reads complete before the first kt staging barrier -> reusing QP as
  // the P buffer afterwards is race-free.

  f32x4 o_[2][4];
#pragma unroll
  for (int g = 0; g < 2; ++g)
#pragma unroll
    for (int c = 0; c < 4; ++c) o_[g][c] = (f32x4){0.f, 0.f, 0.f, 0.f};
  float m_s[2] = {-1e30f, -1e30f};
  float l_s[2] = {0.f, 0.f};

  // K staging geometry (swizzled gld16): wave w covers rows w*16..w*16+15
  const int krow = w * 16 + (lane >> 3);
  const int kcs = (((lane & 7) ^ (lane >> 3)) << 3);  // swizzled ushort col
  const int s7 = col & 7;

  for (int kt = 0; kt < 16; ++kt) {
    // stage K via DMA (swizzled source) and V transposed (reg path)
    {
      const ushort* k0 = K + base + (size_t)(kt * 64 + krow) * 1024 + kcs;
      gld16(k0, &Ks[(w * 16) * 64]);
      gld16(k0 + 8 * 1024, &Ks[(w * 16 + 8) * 64]);
      const int vs = t & 63;
      const int ve = (t >> 6) * 16;
      const ushort* vsrc = V + base + (size_t)(kt * 64 + vs) * 1024 + ve;
      union { uint4 u[2]; ushort s[16]; } vv;
      vv.u[0] = reinterpret_cast<const uint4*>(vsrc)[0];
      vv.u[1] = reinterpret_cast<const uint4*>(vsrc)[1];
#pragma unroll
      for (int j = 0; j < 16; ++j) Vt[(ve + j) * 72 + vs] = vv.s[j];
    }
    __syncthreads();

    // S^T = K Q^T; sc[g][c][r] = S[q=lane&15(+g*16+w*32)][k=c*16+quad*4+r]
    f32x4 sc[2][4];
#pragma unroll
    for (int c = 0; c < 4; ++c) {
      const int R = (c * 16 + col) * 64;
      bf16x8 kb0 = ld8(&Ks[R + ((quad ^ s7) << 3)]);
      bf16x8 kb1 = ld8(&Ks[R + (((quad + 4) ^ s7) << 3)]);
#pragma unroll
      for (int g = 0; g < 2; ++g) {
        f32x4 z = {0.f, 0.f, 0.f, 0.f};
        z = __builtin_amdgcn_mfma_f32_16x16x32_bf16(kb0, qa[g][0], z, 0, 0, 0);
        z = __builtin_amdgcn_mfma_f32_16x16x32_bf16(kb1, qa[g][1], z, 0, 0, 0);
        sc[g][c] = z;
      }
    }

    // online softmax, row-local: in-lane reduce + 2 butterfly steps
    float al[2];
#pragma unroll
    for (int g = 0; g < 2; ++g) {
      float mx = sc[g][0][0];
#pragma unroll
      for (int c = 0; c < 4; ++c)
#pragma unroll
        for (int r = 0; r < 4; ++r) mx = fmaxf(mx, sc[g][c][r]);
      mx = fmaxf(mx, __shfl_xor(mx, 16));
      mx = fmaxf(mx, __shfl_xor(mx, 32));
      const float m_new = fmaxf(m_s[g], mx);
      al[g] = __expf(m_s[g] - m_new);
      m_s[g] = m_new;
      float rs = 0.f;
      const int prow = (w * 32 + g * 16 + col) * 72;
#pragma unroll
      for (int c = 0; c < 4; ++c) {
        const float p0 = __expf(sc[g][c][0] - m_new);
        const float p1 = __expf(sc[g][c][1] - m_new);
        const float p2 = __expf(sc[g][c][2] - m_new);
        const float p3 = __expf(sc[g][c][3] - m_new);
        rs += (p0 + p1) + (p2 + p3);
        union { uint2 u; ushort s[4]; } pk;
        pk.s[0] = f2bf(p0);
        pk.s[1] = f2bf(p1);
        pk.s[2] = f2bf(p2);
        pk.s[3] = f2bf(p3);
        *reinterpret_cast<uint2*>(&QP[prow + c * 16 + quad * 4]) = pk.u;
      }
      rs += __shfl_xor(rs, 16);
      rs += __shfl_xor(rs, 32);
      l_s[g] = l_s[g] * al[g] + rs;
    }

    // rescale O with per-row alpha
#pragma unroll
    for (int g = 0; g < 2; ++g)
#pragma unroll
      for (int r = 0; r < 4; ++r) {
        const float a = __shfl(al[g], (lane & 48) | (quad * 4 + r));
        o_[g][0][r] *= a;
        o_[g][1][r] *= a;
        o_[g][2][r] *= a;
        o_[g][3][r] *= a;
      }

    // O += P V (own-wave P rows; no barrier needed before reads)
    bf16x8 pa[2][2];
#pragma unroll
    for (int g = 0; g < 2; ++g)
#pragma unroll
      for (int half = 0; half < 2; ++half)
        pa[g][half] =
            ld8(&QP[(w * 32 + g * 16 + col) * 72 + half * 32 + quad * 8]);
#pragma unroll
    for (int c = 0; c < 4; ++c) {
      bf16x8 vb0 = ld8(&Vt[(c * 16 + col) * 72 + quad * 8]);
      bf16x8 vb1 = ld8(&Vt[(c * 16 + col) * 72 + 32 + quad * 8]);
#pragma unroll
      for (int g = 0; g < 2; ++g) {
        o_[g][c] = __builtin_amdgcn_mfma_f32_16x16x32_bf16(pa[g][0], vb0,
                                                           o_[g][c], 0, 0, 0);
        o_[g][c] = __builtin_amdgcn_mfma_f32_16x16x32_bf16(pa[g][1], vb1,
                                                           o_[g][c], 0, 0, 0);
      }
    }
    __syncthreads();
  }

#pragma unroll
  for (int g = 0; g < 2; ++g)
#pragma unroll
    for (int r = 0; r < 4; ++r) {
      const float lr = __shfl(l_s[g], (lane & 48) | (quad * 4 + r));
      const float inv = 1.f / lr;
      const size_t row =
          base + (size_t)(qrow0 + w * 32 + g * 16 + quad * 4 + r) * 1024;
      O[row + 0 + col] = f2bf(o_[g][0][r] * inv);
      O[row + 16 + col] = f2bf(o_[g][1][r] * inv);
      O[row + 32 + col] = f2bf(o_[g][2][r] * inv);
      O[row + 48 + col] = f2bf(o_[g][3][r] * inv);
    }
}

// --------------------------------------------------------------------------
extern "C" void kernel_launch(void* const* d_in, const int* in_sizes, int n_in,
                              void* d_out, int out_size, void* d_ws, size_t ws_size,
                              hipStream_t stream) {
  const float* q = (const float*)d_in[0];
  const float* k = (const float*)d_in[1];
  const float* v = (const float*)d_in[2];
  const float* Wq = (const float*)d_in[3];
  const float* Wk = (const float*)d_in[4];
  const float* Wv = (const float*)d_in[5];
  const float* Wo = (const float*)d_in[6];
  const float* bo = (const float*)d_in[7];
  float* out = (float*)d_out;
  ushort* ws = (ushort*)d_ws;

  const size_t M8 = 8u << 20;  // 8M bf16 = 16 MB
  const size_t M1 = 1u << 20;
  ushort* Qp = ws;                 // also flash output (in-place)
  ushort* Kp = ws + M8;
  ushort* Vp = ws + 2 * M8;
  ushort* WqT = ws + 3 * M8;
  ushort* WkT = WqT + M1;
  ushort* WvT = WkT + M1;
  ushort* WoB = WvT + M1;          // total 56 MB

  // d_out (32 MB fp32) as bf16 scratch: q~ at 0, k~ at +16MB; v~ reuses 0.
  ushort* X0 = (ushort*)d_out;
  ushort* X1 = X0 + M8;

  prep_wt3<<<768, 256, 0, stream>>>(Wq, Wk, Wv, WqT, WkT, WvT);
  cvt3<<<4352, 256, 0, stream>>>(q, X0, k, X1, Wo, WoB);
  // attn scale folded into Q projection (exact: 2^-5 exponent shift in bf16)
  gemm_proj2<<<dim3(8, 64, 2), 256, 0, stream>>>(X0, WqT, Qp, 0.03125f,
                                                 X1, WkT, Kp, 1.0f);
  cvt_wo<<<2048, 256, 0, stream>>>(v, X0);
  gemm_bb<false><<<dim3(8, 64), 256, 0, stream>>>(X0, WvT, nullptr, Vp, 1.0f);

  flash_attn<<<1024, 256, 0, stream>>>(Qp, Kp, Vp, Qp);

  gemm_bb<true><<<dim3(8, 64), 256, 0, stream>>>(Qp, WoB, bo, out, 1.0f);
}

// Round 4
// 353.401 us; speedup vs baseline: 1.0877x; 1.0877x over previous
//
#include <hip/hip_runtime.h>
#include <stdint.h>

// ---------------------------------------------------------------------------
// MultiHeadAttention: B=8 S=1024 QKV=1024 H=16 E=64 OUT=1024.
// fp32 in / fp32 out, bf16 MFMA internals, fp32 accum.
// R11:
//  - GEMM dbuf REVERTED (R10 regression: compiler serializes stage->drain->
//    compute via conservative LDS aliasing). Back to R9 single-buffer.
//  - gemm_proj3: q/k/v projections grouped into ONE 1536-block launch
//    (grid 8x192; by<64 q, <128 k, else v). v third reads fp32 input
//    directly (R7-verified stride-72 cvt16 staging for A; B via gld16),
//    so no v~ scratch and no separate cvt launch.
//  - flash: defer-max (T13, THR=8): skip O-rescale + m-update when
//    __all(mx - m <= 8); P bounded by e^8 (bf16-safe). K via gld16+XOR
//    swizzle kept from R10 (verified neutral-correct).
// flash MFMA maps (HW-verified m89/m91):
//   A[m=lane&15][k=quad*8+j], B[k=quad*8+j][n=lane&15], D[row=quad*4+r][col]
// ws: [Qp 16][Kp 16][Vp 16][WqT 2|WkT 2|WvT 2|WoB 2] = 56 MB.
// d_out doubles as bf16 scratch (q~ at 0, k~ at 16MB).
// ---------------------------------------------------------------------------

typedef __bf16 bf16x8 __attribute__((ext_vector_type(8)));
typedef float f32x4 __attribute__((ext_vector_type(4)));

typedef __attribute__((address_space(3))) uint32_t lds_u32;
typedef const __attribute__((address_space(1))) uint32_t glb_u32;

__device__ __forceinline__ ushort f2bf(float f) {
  uint32_t x = __float_as_uint(f);
  x += 0x7fff + ((x >> 16) & 1);  // RNE
  return (ushort)(x >> 16);
}
__device__ __forceinline__ bf16x8 ld8(const ushort* p) {
  union { uint4 u; bf16x8 b; } c;
  c.u = *reinterpret_cast<const uint4*>(p);
  return c.b;
}
__device__ __forceinline__ void cvt16(const float* __restrict__ src,
                                      ushort* __restrict__ dst) {
  union { uint4 u[2]; ushort s[16]; } o;
#pragma unroll
  for (int i = 0; i < 4; ++i) {
    const float4 f = reinterpret_cast<const float4*>(src)[i];
    o.s[4 * i + 0] = f2bf(f.x);
    o.s[4 * i + 1] = f2bf(f.y);
    o.s[4 * i + 2] = f2bf(f.z);
    o.s[4 * i + 3] = f2bf(f.w);
  }
  reinterpret_cast<uint4*>(dst)[0] = o.u[0];
  reinterpret_cast<uint4*>(dst)[1] = o.u[1];
}

// global->LDS DMA, 16B/lane. LDS dest wave-uniform base + lane*16 (m104/m108).
__device__ __forceinline__ void gld16(const ushort* g, ushort* l) {
  __builtin_amdgcn_global_load_lds((glb_u32*)g, (lds_u32*)l, 16, 0, 0);
}

// --------------------------------------------------------------------------
// W[16][1024][64] fp32 -> WT[1024][1024] bf16 (WT[n=h*64+e][k]).
// 3 weights in one launch: grid 768 (bid>>8 selects W). 256 thr.
// --------------------------------------------------------------------------
__global__ __launch_bounds__(256) void prep_wt3(
    const float* __restrict__ W0, const float* __restrict__ W1,
    const float* __restrict__ W2, ushort* __restrict__ T0,
    ushort* __restrict__ T1, ushort* __restrict__ T2) {
  __shared__ __align__(16) ushort tile[64 * 72];
  const int sel = blockIdx.x >> 8;
  const float* W = sel == 0 ? W0 : sel == 1 ? W1 : W2;
  ushort* WT = sel == 0 ? T0 : sel == 1 ? T1 : T2;
  const int bid = blockIdx.x & 255;
  const int h = bid >> 4;
  const int kt = bid & 15;
  const int t = threadIdx.x;
  const int row = t >> 2;
  const int ch = (t & 3) * 16;
  cvt16(W + ((size_t)h * 1024 + kt * 64 + row) * 64 + ch, &tile[row * 72 + ch]);
  __syncthreads();
  const int e = t >> 2;
  const int kc = (t & 3) * 16;
  ushort vals[16];
#pragma unroll
  for (int j = 0; j < 16; ++j) vals[j] = tile[(kc + j) * 72 + e];
  ushort* dst = WT + (size_t)(h * 64 + e) * 1024 + kt * 64 + kc;
  reinterpret_cast<uint4*>(dst)[0] = *reinterpret_cast<uint4*>(&vals[0]);
  reinterpret_cast<uint4*>(dst)[1] = *reinterpret_cast<uint4*>(&vals[8]);
}

// q (8M) + k (8M) + Wo (1M) fp32->bf16 in one launch. grid 4352.
__global__ __launch_bounds__(256) void cvt3(const float* __restrict__ s0,
                                            ushort* __restrict__ d0,
                                            const float* __restrict__ s1,
                                            ushort* __restrict__ d1,
                                            const float* __restrict__ s2,
                                            ushort* __restrict__ d2) {
  int b = blockIdx.x;
  const float* s;
  ushort* d;
  if (b < 2048) { s = s0; d = d0; }
  else if (b < 4096) { s = s1; d = d1; b -= 2048; }
  else { s = s2; d = d2; b -= 4096; }
  const int i = (b * 256 + threadIdx.x) * 16;
  cvt16(s + i, d + i);
}

// --------------------------------------------------------------------------
// GEMM core (bf16 A): C[.][1024] = A bf16 @ Bt bf16 ^T (*oscale, + bias).
// 128x128 tile, BK=64, 4 waves 2x2, linear LDS (stride 64), gld16 staging,
// single-buffer 2-barrier K-loop (R9 structure — verified).
// --------------------------------------------------------------------------
template <bool F32OUT>
__device__ __forceinline__ void core_bb(ushort* __restrict__ As,
                                        ushort* __restrict__ Bs,
                                        const ushort* __restrict__ A,
                                        const ushort* __restrict__ Bt,
                                        const float* __restrict__ bias,
                                        void* __restrict__ Cv, float oscale,
                                        int bx, int by) {
  const int n0 = bx * 128;
  const int m0 = by * 128;
  const int t = threadIdx.x;
  const int lane = t & 63;
  const int w = t >> 6;
  const int wm = w >> 1, wn = w & 1;
  const int col = lane & 15;
  const int quad = lane >> 4;
  const int gr = lane >> 3;        // 0..7
  const int gc = (lane & 7) * 8;   // ushort col 0..56

  f32x4 acc[4][4];
#pragma unroll
  for (int i = 0; i < 4; ++i)
#pragma unroll
    for (int j = 0; j < 4; ++j) acc[i][j] = (f32x4){0.f, 0.f, 0.f, 0.f};

  const ushort* a_src = A + (size_t)(m0 + w * 8 + gr) * 1024 + gc;
  const ushort* b_src = Bt + (size_t)(n0 + w * 8 + gr) * 1024 + gc;
  ushort* as_base = &As[(w * 8) * 64];
  ushort* bs_base = &Bs[(w * 8) * 64];

  for (int k0 = 0; k0 < 1024; k0 += 64) {
#pragma unroll
    for (int c = 0; c < 4; ++c) {
      gld16(a_src + (size_t)c * 32 * 1024 + k0, as_base + c * 32 * 64);
      gld16(b_src + (size_t)c * 32 * 1024 + k0, bs_base + c * 32 * 64);
    }
    __syncthreads();

#pragma unroll
    for (int half = 0; half < 2; ++half) {
      bf16x8 af[4], bfr[4];
#pragma unroll
      for (int i = 0; i < 4; ++i)
        af[i] = ld8(&As[(wm * 64 + i * 16 + col) * 64 + half * 32 + quad * 8]);
#pragma unroll
      for (int j = 0; j < 4; ++j)
        bfr[j] = ld8(&Bs[(wn * 64 + j * 16 + col) * 64 + half * 32 + quad * 8]);
#pragma unroll
      for (int i = 0; i < 4; ++i)
#pragma unroll
        for (int j = 0; j < 4; ++j)
          acc[i][j] = __builtin_amdgcn_mfma_f32_16x16x32_bf16(af[i], bfr[j],
                                                              acc[i][j], 0, 0, 0);
    }
    __syncthreads();
  }

#pragma unroll
  for (int i = 0; i < 4; ++i)
#pragma unroll
    for (int j = 0; j < 4; ++j) {
      const int n = n0 + wn * 64 + j * 16 + col;
      float bv = 0.f;
      if (F32OUT) bv = bias[n];
#pragma unroll
      for (int r = 0; r < 4; ++r) {
        const int m = m0 + wm * 64 + i * 16 + quad * 4 + r;
        if (F32OUT)
          reinterpret_cast<float*>(Cv)[(size_t)m * 1024 + n] = acc[i][j][r] + bv;
        else
          reinterpret_cast<ushort*>(Cv)[(size_t)m * 1024 + n] =
              f2bf(acc[i][j][r] * oscale);
      }
    }
}

// --------------------------------------------------------------------------
// GEMM core (fp32 A, in-kernel cvt): A staged via cvt16 into stride-72 LDS
// (R7-verified layout; 72 breaks the 128B-row bank alias), B via gld16.
// --------------------------------------------------------------------------
__device__ __forceinline__ void core_f32a(ushort* __restrict__ As72,
                                          ushort* __restrict__ Bs,
                                          const float* __restrict__ A,
                                          const ushort* __restrict__ Bt,
                                          ushort* __restrict__ C, int bx,
                                          int by) {
  const int n0 = bx * 128;
  const int m0 = by * 128;
  const int t = threadIdx.x;
  const int lane = t & 63;
  const int w = t >> 6;
  const int wm = w >> 1, wn = w & 1;
  const int col = lane & 15;
  const int quad = lane >> 4;
  const int gr = lane >> 3;
  const int gc = (lane & 7) * 8;
  const int srow = t >> 1;        // 0..127
  const int sc0 = (t & 1) * 32;   // 0 or 32

  f32x4 acc[4][4];
#pragma unroll
  for (int i = 0; i < 4; ++i)
#pragma unroll
    for (int j = 0; j < 4; ++j) acc[i][j] = (f32x4){0.f, 0.f, 0.f, 0.f};

  const float* a_src = A + (size_t)(m0 + srow) * 1024 + sc0;
  const ushort* b_src = Bt + (size_t)(n0 + w * 8 + gr) * 1024 + gc;
  ushort* bs_base = &Bs[(w * 8) * 64];

  for (int k0 = 0; k0 < 1024; k0 += 64) {
#pragma unroll
    for (int c = 0; c < 4; ++c)
      gld16(b_src + (size_t)c * 32 * 1024 + k0, bs_base + c * 32 * 64);
    cvt16(a_src + k0, &As72[srow * 72 + sc0]);
    cvt16(a_src + k0 + 16, &As72[srow * 72 + sc0 + 16]);
    __syncthreads();

#pragma unroll
    for (int half = 0; half < 2; ++half) {
      bf16x8 af[4], bfr[4];
#pragma unroll
      for (int i = 0; i < 4; ++i)
        af[i] = ld8(&As72[(wm * 64 + i * 16 + col) * 72 + half * 32 + quad * 8]);
#pragma unroll
      for (int j = 0; j < 4; ++j)
        bfr[j] = ld8(&Bs[(wn * 64 + j * 16 + col) * 64 + half * 32 + quad * 8]);
#pragma unroll
      for (int i = 0; i < 4; ++i)
#pragma unroll
        for (int j = 0; j < 4; ++j)
          acc[i][j] = __builtin_amdgcn_mfma_f32_16x16x32_bf16(af[i], bfr[j],
                                                              acc[i][j], 0, 0, 0);
    }
    __syncthreads();
  }

#pragma unroll
  for (int i = 0; i < 4; ++i)
#pragma unroll
    for (int j = 0; j < 4; ++j) {
      const int n = n0 + wn * 64 + j * 16 + col;
#pragma unroll
      for (int r = 0; r < 4; ++r) {
        const int m = m0 + wm * 64 + i * 16 + quad * 4 + r;
        C[(size_t)m * 1024 + n] = f2bf(acc[i][j][r]);
      }
    }
}

// OUT gemm: C fp32 + bias. grid dim3(8, 64).
__global__ __launch_bounds__(256) void gemm_out(const ushort* __restrict__ A,
                                                const ushort* __restrict__ Bt,
                                                const float* __restrict__ bias,
                                                float* __restrict__ C) {
  __shared__ __align__(16) ushort As[128 * 64];
  __shared__ __align__(16) ushort Bs[128 * 64];
  core_bb<true>(As, Bs, A, Bt, bias, C, 1.0f, blockIdx.x, blockIdx.y);
}

// All three projections in one launch. grid dim3(8, 192) = 1536 blocks.
// by<64: q (bf16, scale 2^-5 folded); <128: k (bf16); else: v (fp32 direct).
__global__ __launch_bounds__(256) void gemm_proj3(
    const ushort* __restrict__ Aq, const ushort* __restrict__ Bq,
    ushort* __restrict__ Cq, const ushort* __restrict__ Ak,
    const ushort* __restrict__ Bk, ushort* __restrict__ Ck,
    const float* __restrict__ Av, const ushort* __restrict__ Bv,
    ushort* __restrict__ Cvp) {
  __shared__ __align__(16) ushort As[128 * 72];  // stride 64 (q/k) or 72 (v)
  __shared__ __align__(16) ushort Bs[128 * 64];
  const int by = blockIdx.y;
  if (by < 64)
    core_bb<false>(As, Bs, Aq, Bq, nullptr, Cq, 0.03125f, blockIdx.x, by);
  else if (by < 128)
    core_bb<false>(As, Bs, Ak, Bk, nullptr, Ck, 1.0f, blockIdx.x, by - 64);
  else
    core_f32a(As, Bs, Av, Bv, Cvp, blockIdx.x, by - 128);
}

// --------------------------------------------------------------------------
// Flash attention, 128-row q-tiles. Q,K,V,O bf16 [8192][1024], O aliases Q.
// Q PRE-SCALED by 1/sqrt(1024). grid 1024; block 256 (4 waves); wave w owns
// q-rows w*32..+31. Swapped QK^T (lane-local softmax rows). K staged via
// gld16 + granule XOR swizzle into linear Ks[64][64]. Defer-max (THR=8):
// skip O-rescale + m-update while __all(mx - m <= 8); P bounded by e^8.
// Barriers: 2/kt. LDS 35 KB.
// --------------------------------------------------------------------------
__global__ __launch_bounds__(256) void flash_attn(const ushort* __restrict__ Q,
                                                  const ushort* __restrict__ K,
                                                  const ushort* __restrict__ V,
                                                  ushort* __restrict__ O) {
  __shared__ __align__(16) ushort QP[128 * 72];
  __shared__ __align__(16) ushort Ks[64 * 64];
  __shared__ __align__(16) ushort Vt[64 * 72];
  const int pair = blockIdx.x & 127;
  const int b = pair >> 4;
  const int h = pair & 15;
  const int qt = blockIdx.x >> 7;
  const int t = threadIdx.x;
  const int lane = t & 63;
  const int w = t >> 6;
  const int col = lane & 15;
  const int quad = lane >> 4;

  const size_t base = (size_t)b * 1024 * 1024 + h * 64;
  const int qrow0 = qt * 128;

  // stage Q (128 x 64): 32 ushorts per thread
  {
    const int row = t >> 1;
    const int c0 = (t & 1) * 32;
    const ushort* src = Q + base + (size_t)(qrow0 + row) * 1024 + c0;
    uint4 v0 = reinterpret_cast<const uint4*>(src)[0];
    uint4 v1 = reinterpret_cast<const uint4*>(src)[1];
    uint4 v2 = reinterpret_cast<const uint4*>(src)[2];
    uint4 v3 = reinterpret_cast<const uint4*>(src)[3];
    reinterpret_cast<uint4*>(&QP[row * 72 + c0])[0] = v0;
    reinterpret_cast<uint4*>(&QP[row * 72 + c0])[1] = v1;
    reinterpret_cast<uint4*>(&QP[row * 72 + c0])[2] = v2;
    reinterpret_cast<uint4*>(&QP[row * 72 + c0])[3] = v3;
  }
  __syncthreads();
  bf16x8 qa[2][2];
#pragma unroll
  for (int g = 0; g < 2; ++g)
#pragma unroll
    for (int half = 0; half < 2; ++half)
      qa[g][half] =
          ld8(&QP[(w * 32 + g * 16 + col) * 72 + half * 32 + quad * 8]);
  // qa reads complete before the first kt staging barrier -> reusing QP as
  // the P buffer afterwards is race-free.

  f32x4 o_[2][4];
#pragma unroll
  for (int g = 0; g < 2; ++g)
#pragma unroll
    for (int c = 0; c < 4; ++c) o_[g][c] = (f32x4){0.f, 0.f, 0.f, 0.f};
  float m_s[2] = {-1e30f, -1e30f};
  float l_s[2] = {0.f, 0.f};

  // K staging geometry (swizzled gld16): wave w covers rows w*16..w*16+15
  const int krow = w * 16 + (lane >> 3);
  const int kcs = (((lane & 7) ^ (lane >> 3)) << 3);  // swizzled ushort col
  const int s7 = col & 7;

  for (int kt = 0; kt < 16; ++kt) {
    // stage K via DMA (swizzled source) and V transposed (reg path)
    {
      const ushort* k0 = K + base + (size_t)(kt * 64 + krow) * 1024 + kcs;
      gld16(k0, &Ks[(w * 16) * 64]);
      gld16(k0 + 8 * 1024, &Ks[(w * 16 + 8) * 64]);
      const int vs = t & 63;
      const int ve = (t >> 6) * 16;
      const ushort* vsrc = V + base + (size_t)(kt * 64 + vs) * 1024 + ve;
      union { uint4 u[2]; ushort s[16]; } vv;
      vv.u[0] = reinterpret_cast<const uint4*>(vsrc)[0];
      vv.u[1] = reinterpret_cast<const uint4*>(vsrc)[1];
#pragma unroll
      for (int j = 0; j < 16; ++j) Vt[(ve + j) * 72 + vs] = vv.s[j];
    }
    __syncthreads();

    // S^T = K Q^T; sc[g][c][r] = S[q=lane&15(+g*16+w*32)][k=c*16+quad*4+r]
    f32x4 sc[2][4];
#pragma unroll
    for (int c = 0; c < 4; ++c) {
      const int R = (c * 16 + col) * 64;
      bf16x8 kb0 = ld8(&Ks[R + ((quad ^ s7) << 3)]);
      bf16x8 kb1 = ld8(&Ks[R + (((quad + 4) ^ s7) << 3)]);
#pragma unroll
      for (int g = 0; g < 2; ++g) {
        f32x4 z = {0.f, 0.f, 0.f, 0.f};
        z = __builtin_amdgcn_mfma_f32_16x16x32_bf16(kb0, qa[g][0], z, 0, 0, 0);
        z = __builtin_amdgcn_mfma_f32_16x16x32_bf16(kb1, qa[g][1], z, 0, 0, 0);
        sc[g][c] = z;
      }
    }

    // online softmax, row-local, with defer-max (THR=8)
    float al[2];
    bool df[2];
#pragma unroll
    for (int g = 0; g < 2; ++g) {
      float mx = sc[g][0][0];
#pragma unroll
      for (int c = 0; c < 4; ++c)
#pragma unroll
        for (int r = 0; r < 4; ++r) mx = fmaxf(mx, sc[g][c][r]);
      mx = fmaxf(mx, __shfl_xor(mx, 16));
      mx = fmaxf(mx, __shfl_xor(mx, 32));
      df[g] = __all(mx - m_s[g] <= 8.0f) != 0;
      if (df[g]) {
        al[g] = 1.0f;
      } else {
        const float m_new = fmaxf(m_s[g], mx);
        al[g] = __expf(m_s[g] - m_new);
        m_s[g] = m_new;
      }
      float rs = 0.f;
      const int prow = (w * 32 + g * 16 + col) * 72;
#pragma unroll
      for (int c = 0; c < 4; ++c) {
        const float p0 = __expf(sc[g][c][0] - m_s[g]);
        const float p1 = __expf(sc[g][c][1] - m_s[g]);
        const float p2 = __expf(sc[g][c][2] - m_s[g]);
        const float p3 = __expf(sc[g][c][3] - m_s[g]);
        rs += (p0 + p1) + (p2 + p3);
        union { uint2 u; ushort s[4]; } pk;
        pk.s[0] = f2bf(p0);
        pk.s[1] = f2bf(p1);
        pk.s[2] = f2bf(p2);
        pk.s[3] = f2bf(p3);
        *reinterpret_cast<uint2*>(&QP[prow + c * 16 + quad * 4]) = pk.u;
      }
      rs += __shfl_xor(rs, 16);
      rs += __shfl_xor(rs, 32);
      l_s[g] = df[g] ? (l_s[g] + rs) : (l_s[g] * al[g] + rs);
    }

    // rescale O with per-row alpha (skipped entirely when deferred)
#pragma unroll
    for (int g = 0; g < 2; ++g)
      if (!df[g]) {
#pragma unroll
        for (int r = 0; r < 4; ++r) {
          const float a = __shfl(al[g], (lane & 48) | (quad * 4 + r));
          o_[g][0][r] *= a;
          o_[g][1][r] *= a;
          o_[g][2][r] *= a;
          o_[g][3][r] *= a;
        }
      }

    // O += P V (own-wave P rows; no barrier needed before reads)
    bf16x8 pa[2][2];
#pragma unroll
    for (int g = 0; g < 2; ++g)
#pragma unroll
      for (int half = 0; half < 2; ++half)
        pa[g][half] =
            ld8(&QP[(w * 32 + g * 16 + col) * 72 + half * 32 + quad * 8]);
#pragma unroll
    for (int c = 0; c < 4; ++c) {
      bf16x8 vb0 = ld8(&Vt[(c * 16 + col) * 72 + quad * 8]);
      bf16x8 vb1 = ld8(&Vt[(c * 16 + col) * 72 + 32 + quad * 8]);
#pragma unroll
      for (int g = 0; g < 2; ++g) {
        o_[g][c] = __builtin_amdgcn_mfma_f32_16x16x32_bf16(pa[g][0], vb0,
                                                           o_[g][c], 0, 0, 0);
        o_[g][c] = __builtin_amdgcn_mfma_f32_16x16x32_bf16(pa[g][1], vb1,
                                                           o_[g][c], 0, 0, 0);
      }
    }
    __syncthreads();
  }

#pragma unroll
  for (int g = 0; g < 2; ++g)
#pragma unroll
    for (int r = 0; r < 4; ++r) {
      const float lr = __shfl(l_s[g], (lane & 48) | (quad * 4 + r));
      const float inv = 1.f / lr;
      const size_t row =
          base + (size_t)(qrow0 + w * 32 + g * 16 + quad * 4 + r) * 1024;
      O[row + 0 + col] = f2bf(o_[g][0][r] * inv);
      O[row + 16 + col] = f2bf(o_[g][1][r] * inv);
      O[row + 32 + col] = f2bf(o_[g][2][r] * inv);
      O[row + 48 + col] = f2bf(o_[g][3][r] * inv);
    }
}

// --------------------------------------------------------------------------
extern "C" void kernel_launch(void* const* d_in, const int* in_sizes, int n_in,
                              void* d_out, int out_size, void* d_ws, size_t ws_size,
                              hipStream_t stream) {
  const float* q = (const float*)d_in[0];
  const float* k = (const float*)d_in[1];
  const float* v = (const float*)d_in[2];
  const float* Wq = (const float*)d_in[3];
  const float* Wk = (const float*)d_in[4];
  const float* Wv = (const float*)d_in[5];
  const float* Wo = (const float*)d_in[6];
  const float* bo = (const float*)d_in[7];
  float* out = (float*)d_out;
  ushort* ws = (ushort*)d_ws;

  const size_t M8 = 8u << 20;  // 8M bf16 = 16 MB
  const size_t M1 = 1u << 20;
  ushort* Qp = ws;                 // also flash output (in-place)
  ushort* Kp = ws + M8;
  ushort* Vp = ws + 2 * M8;
  ushort* WqT = ws + 3 * M8;
  ushort* WkT = WqT + M1;
  ushort* WvT = WkT + M1;
  ushort* WoB = WvT + M1;          // total 56 MB

  // d_out (32 MB fp32) as bf16 scratch: q~ at 0, k~ at +16MB.
  ushort* X0 = (ushort*)d_out;
  ushort* X1 = X0 + M8;

  prep_wt3<<<768, 256, 0, stream>>>(Wq, Wk, Wv, WqT, WkT, WvT);
  cvt3<<<4352, 256, 0, stream>>>(q, X0, k, X1, Wo, WoB);
  // attn scale folded into Q projection (exact: 2^-5 exponent shift in bf16)
  gemm_proj3<<<dim3(8, 192), 256, 0, stream>>>(X0, WqT, Qp, X1, WkT, Kp,
                                               v, WvT, Vp);

  flash_attn<<<1024, 256, 0, stream>>>(Qp, Kp, Vp, Qp);

  gemm_out<<<dim3(8, 64), 256, 0, stream>>>(Qp, WoB, bo, out);
}

// Round 5
// 352.389 us; speedup vs baseline: 1.0909x; 1.0029x over previous
//
#include <hip/hip_runtime.h>
#include <stdint.h>

// ---------------------------------------------------------------------------
// MultiHeadAttention: B=8 S=1024 QKV=1024 H=16 E=64 OUT=1024.
// fp32 in / fp32 out, bf16 MFMA internals, fp32 accum.
// R12: XCD-chunked swizzle for gemm_proj3 / gemm_out (T1, m192/m204).
//   R11 counters: proj3 FETCH=265MB vs ~70MB ideal. Cause: dim3(8,192) grid
//   -> XCD = linear%8 = bx, so the 8 blocks sharing an A-row panel live on
//   8 different (non-coherent) L2s -> 8x A fetch. New 1D grid decode:
//     id = 64*a + 8*bx + b,  by = 8*a + b, bx = (id>>3)&7
//   -> same-by group: same XCD (id%8=b), adjacent dispatch; per-XCD working
//   set = 8 A-panels (2MB) + weight (2MB) = 4MB = L2. A fetched once total.
//   Same decode for gemm_out. flash_attn unchanged (control).
// R11 kept: single-buffer GEMM (dbuf regressed), proj3 fusion (v reads fp32
// via stride-72 cvt16 staging), flash defer-max + swapped QK^T + K gld16.
// flash MFMA maps (HW-verified m89/m91):
//   A[m=lane&15][k=quad*8+j], B[k=quad*8+j][n=lane&15], D[row=quad*4+r][col]
// ws: [Qp 16][Kp 16][Vp 16][WqT 2|WkT 2|WvT 2|WoB 2] = 56 MB.
// d_out doubles as bf16 scratch (q~ at 0, k~ at 16MB).
// ---------------------------------------------------------------------------

typedef __bf16 bf16x8 __attribute__((ext_vector_type(8)));
typedef float f32x4 __attribute__((ext_vector_type(4)));

typedef __attribute__((address_space(3))) uint32_t lds_u32;
typedef const __attribute__((address_space(1))) uint32_t glb_u32;

__device__ __forceinline__ ushort f2bf(float f) {
  uint32_t x = __float_as_uint(f);
  x += 0x7fff + ((x >> 16) & 1);  // RNE
  return (ushort)(x >> 16);
}
__device__ __forceinline__ bf16x8 ld8(const ushort* p) {
  union { uint4 u; bf16x8 b; } c;
  c.u = *reinterpret_cast<const uint4*>(p);
  return c.b;
}
__device__ __forceinline__ void cvt16(const float* __restrict__ src,
                                      ushort* __restrict__ dst) {
  union { uint4 u[2]; ushort s[16]; } o;
#pragma unroll
  for (int i = 0; i < 4; ++i) {
    const float4 f = reinterpret_cast<const float4*>(src)[i];
    o.s[4 * i + 0] = f2bf(f.x);
    o.s[4 * i + 1] = f2bf(f.y);
    o.s[4 * i + 2] = f2bf(f.z);
    o.s[4 * i + 3] = f2bf(f.w);
  }
  reinterpret_cast<uint4*>(dst)[0] = o.u[0];
  reinterpret_cast<uint4*>(dst)[1] = o.u[1];
}

// global->LDS DMA, 16B/lane. LDS dest wave-uniform base + lane*16 (m104/m108).
__device__ __forceinline__ void gld16(const ushort* g, ushort* l) {
  __builtin_amdgcn_global_load_lds((glb_u32*)g, (lds_u32*)l, 16, 0, 0);
}

// --------------------------------------------------------------------------
// W[16][1024][64] fp32 -> WT[1024][1024] bf16 (WT[n=h*64+e][k]).
// 3 weights in one launch: grid 768 (bid>>8 selects W). 256 thr.
// --------------------------------------------------------------------------
__global__ __launch_bounds__(256) void prep_wt3(
    const float* __restrict__ W0, const float* __restrict__ W1,
    const float* __restrict__ W2, ushort* __restrict__ T0,
    ushort* __restrict__ T1, ushort* __restrict__ T2) {
  __shared__ __align__(16) ushort tile[64 * 72];
  const int sel = blockIdx.x >> 8;
  const float* W = sel == 0 ? W0 : sel == 1 ? W1 : W2;
  ushort* WT = sel == 0 ? T0 : sel == 1 ? T1 : T2;
  const int bid = blockIdx.x & 255;
  const int h = bid >> 4;
  const int kt = bid & 15;
  const int t = threadIdx.x;
  const int row = t >> 2;
  const int ch = (t & 3) * 16;
  cvt16(W + ((size_t)h * 1024 + kt * 64 + row) * 64 + ch, &tile[row * 72 + ch]);
  __syncthreads();
  const int e = t >> 2;
  const int kc = (t & 3) * 16;
  ushort vals[16];
#pragma unroll
  for (int j = 0; j < 16; ++j) vals[j] = tile[(kc + j) * 72 + e];
  ushort* dst = WT + (size_t)(h * 64 + e) * 1024 + kt * 64 + kc;
  reinterpret_cast<uint4*>(dst)[0] = *reinterpret_cast<uint4*>(&vals[0]);
  reinterpret_cast<uint4*>(dst)[1] = *reinterpret_cast<uint4*>(&vals[8]);
}

// q (8M) + k (8M) + Wo (1M) fp32->bf16 in one launch. grid 4352.
__global__ __launch_bounds__(256) void cvt3(const float* __restrict__ s0,
                                            ushort* __restrict__ d0,
                                            const float* __restrict__ s1,
                                            ushort* __restrict__ d1,
                                            const float* __restrict__ s2,
                                            ushort* __restrict__ d2) {
  int b = blockIdx.x;
  const float* s;
  ushort* d;
  if (b < 2048) { s = s0; d = d0; }
  else if (b < 4096) { s = s1; d = d1; b -= 2048; }
  else { s = s2; d = d2; b -= 4096; }
  const int i = (b * 256 + threadIdx.x) * 16;
  cvt16(s + i, d + i);
}

// --------------------------------------------------------------------------
// GEMM core (bf16 A): C[.][1024] = A bf16 @ Bt bf16 ^T (*oscale, + bias).
// 128x128 tile, BK=64, 4 waves 2x2, linear LDS (stride 64), gld16 staging,
// single-buffer 2-barrier K-loop (R9 structure — verified).
// --------------------------------------------------------------------------
template <bool F32OUT>
__device__ __forceinline__ void core_bb(ushort* __restrict__ As,
                                        ushort* __restrict__ Bs,
                                        const ushort* __restrict__ A,
                                        const ushort* __restrict__ Bt,
                                        const float* __restrict__ bias,
                                        void* __restrict__ Cv, float oscale,
                                        int bx, int by) {
  const int n0 = bx * 128;
  const int m0 = by * 128;
  const int t = threadIdx.x;
  const int lane = t & 63;
  const int w = t >> 6;
  const int wm = w >> 1, wn = w & 1;
  const int col = lane & 15;
  const int quad = lane >> 4;
  const int gr = lane >> 3;        // 0..7
  const int gc = (lane & 7) * 8;   // ushort col 0..56

  f32x4 acc[4][4];
#pragma unroll
  for (int i = 0; i < 4; ++i)
#pragma unroll
    for (int j = 0; j < 4; ++j) acc[i][j] = (f32x4){0.f, 0.f, 0.f, 0.f};

  const ushort* a_src = A + (size_t)(m0 + w * 8 + gr) * 1024 + gc;
  const ushort* b_src = Bt + (size_t)(n0 + w * 8 + gr) * 1024 + gc;
  ushort* as_base = &As[(w * 8) * 64];
  ushort* bs_base = &Bs[(w * 8) * 64];

  for (int k0 = 0; k0 < 1024; k0 += 64) {
#pragma unroll
    for (int c = 0; c < 4; ++c) {
      gld16(a_src + (size_t)c * 32 * 1024 + k0, as_base + c * 32 * 64);
      gld16(b_src + (size_t)c * 32 * 1024 + k0, bs_base + c * 32 * 64);
    }
    __syncthreads();

#pragma unroll
    for (int half = 0; half < 2; ++half) {
      bf16x8 af[4], bfr[4];
#pragma unroll
      for (int i = 0; i < 4; ++i)
        af[i] = ld8(&As[(wm * 64 + i * 16 + col) * 64 + half * 32 + quad * 8]);
#pragma unroll
      for (int j = 0; j < 4; ++j)
        bfr[j] = ld8(&Bs[(wn * 64 + j * 16 + col) * 64 + half * 32 + quad * 8]);
#pragma unroll
      for (int i = 0; i < 4; ++i)
#pragma unroll
        for (int j = 0; j < 4; ++j)
          acc[i][j] = __builtin_amdgcn_mfma_f32_16x16x32_bf16(af[i], bfr[j],
                                                              acc[i][j], 0, 0, 0);
    }
    __syncthreads();
  }

#pragma unroll
  for (int i = 0; i < 4; ++i)
#pragma unroll
    for (int j = 0; j < 4; ++j) {
      const int n = n0 + wn * 64 + j * 16 + col;
      float bv = 0.f;
      if (F32OUT) bv = bias[n];
#pragma unroll
      for (int r = 0; r < 4; ++r) {
        const int m = m0 + wm * 64 + i * 16 + quad * 4 + r;
        if (F32OUT)
          reinterpret_cast<float*>(Cv)[(size_t)m * 1024 + n] = acc[i][j][r] + bv;
        else
          reinterpret_cast<ushort*>(Cv)[(size_t)m * 1024 + n] =
              f2bf(acc[i][j][r] * oscale);
      }
    }
}

// --------------------------------------------------------------------------
// GEMM core (fp32 A, in-kernel cvt): A staged via cvt16 into stride-72 LDS
// (R7-verified layout; 72 breaks the 128B-row bank alias), B via gld16.
// --------------------------------------------------------------------------
__device__ __forceinline__ void core_f32a(ushort* __restrict__ As72,
                                          ushort* __restrict__ Bs,
                                          const float* __restrict__ A,
                                          const ushort* __restrict__ Bt,
                                          ushort* __restrict__ C, int bx,
                                          int by) {
  const int n0 = bx * 128;
  const int m0 = by * 128;
  const int t = threadIdx.x;
  const int lane = t & 63;
  const int w = t >> 6;
  const int wm = w >> 1, wn = w & 1;
  const int col = lane & 15;
  const int quad = lane >> 4;
  const int gr = lane >> 3;
  const int gc = (lane & 7) * 8;
  const int srow = t >> 1;        // 0..127
  const int sc0 = (t & 1) * 32;   // 0 or 32

  f32x4 acc[4][4];
#pragma unroll
  for (int i = 0; i < 4; ++i)
#pragma unroll
    for (int j = 0; j < 4; ++j) acc[i][j] = (f32x4){0.f, 0.f, 0.f, 0.f};

  const float* a_src = A + (size_t)(m0 + srow) * 1024 + sc0;
  const ushort* b_src = Bt + (size_t)(n0 + w * 8 + gr) * 1024 + gc;
  ushort* bs_base = &Bs[(w * 8) * 64];

  for (int k0 = 0; k0 < 1024; k0 += 64) {
#pragma unroll
    for (int c = 0; c < 4; ++c)
      gld16(b_src + (size_t)c * 32 * 1024 + k0, bs_base + c * 32 * 64);
    cvt16(a_src + k0, &As72[srow * 72 + sc0]);
    cvt16(a_src + k0 + 16, &As72[srow * 72 + sc0 + 16]);
    __syncthreads();

#pragma unroll
    for (int half = 0; half < 2; ++half) {
      bf16x8 af[4], bfr[4];
#pragma unroll
      for (int i = 0; i < 4; ++i)
        af[i] = ld8(&As72[(wm * 64 + i * 16 + col) * 72 + half * 32 + quad * 8]);
#pragma unroll
      for (int j = 0; j < 4; ++j)
        bfr[j] = ld8(&Bs[(wn * 64 + j * 16 + col) * 64 + half * 32 + quad * 8]);
#pragma unroll
      for (int i = 0; i < 4; ++i)
#pragma unroll
        for (int j = 0; j < 4; ++j)
          acc[i][j] = __builtin_amdgcn_mfma_f32_16x16x32_bf16(af[i], bfr[j],
                                                              acc[i][j], 0, 0, 0);
    }
    __syncthreads();
  }

#pragma unroll
  for (int i = 0; i < 4; ++i)
#pragma unroll
    for (int j = 0; j < 4; ++j) {
      const int n = n0 + wn * 64 + j * 16 + col;
#pragma unroll
      for (int r = 0; r < 4; ++r) {
        const int m = m0 + wm * 64 + i * 16 + quad * 4 + r;
        C[(size_t)m * 1024 + n] = f2bf(acc[i][j][r]);
      }
    }
}

// OUT gemm: C fp32 + bias. grid 512 (1D, XCD-chunked decode).
// id = 64*a + 8*bx + b; by = 8*a + b -> same-by group on one XCD, adjacent.
__global__ __launch_bounds__(256) void gemm_out(const ushort* __restrict__ A,
                                                const ushort* __restrict__ Bt,
                                                const float* __restrict__ bias,
                                                float* __restrict__ C) {
  __shared__ __align__(16) ushort As[128 * 64];
  __shared__ __align__(16) ushort Bs[128 * 64];
  const int id = blockIdx.x;
  const int bx = (id >> 3) & 7;
  const int by = ((id >> 6) << 3) | (id & 7);
  core_bb<true>(As, Bs, A, Bt, bias, C, 1.0f, bx, by);
}

// All three projections in one launch. grid 1536 (1D, XCD-chunked decode).
// id = 64*a + 8*bx + b; by = 8*a + b (0..191). by<64: q (scale 2^-5 folded);
// <128: k; else: v (fp32 A). Per-XCD working set: 8 A-panels + weight = 4MB.
__global__ __launch_bounds__(256) void gemm_proj3(
    const ushort* __restrict__ Aq, const ushort* __restrict__ Bq,
    ushort* __restrict__ Cq, const ushort* __restrict__ Ak,
    const ushort* __restrict__ Bk, ushort* __restrict__ Ck,
    const float* __restrict__ Av, const ushort* __restrict__ Bv,
    ushort* __restrict__ Cvp) {
  __shared__ __align__(16) ushort As[128 * 72];  // stride 64 (q/k) or 72 (v)
  __shared__ __align__(16) ushort Bs[128 * 64];
  const int id = blockIdx.x;
  const int bx = (id >> 3) & 7;
  const int by = ((id >> 6) << 3) | (id & 7);
  if (by < 64)
    core_bb<false>(As, Bs, Aq, Bq, nullptr, Cq, 0.03125f, bx, by);
  else if (by < 128)
    core_bb<false>(As, Bs, Ak, Bk, nullptr, Ck, 1.0f, bx, by - 64);
  else
    core_f32a(As, Bs, Av, Bv, Cvp, bx, by - 128);
}

// --------------------------------------------------------------------------
// Flash attention, 128-row q-tiles. Q,K,V,O bf16 [8192][1024], O aliases Q.
// Q PRE-SCALED by 1/sqrt(1024). grid 1024; block 256 (4 waves); wave w owns
// q-rows w*32..+31. Swapped QK^T (lane-local softmax rows). K staged via
// gld16 + granule XOR swizzle into linear Ks[64][64]. Defer-max (THR=8).
// Barriers: 2/kt. LDS 35 KB. UNCHANGED from R11 (control).
// --------------------------------------------------------------------------
__global__ __launch_bounds__(256) void flash_attn(const ushort* __restrict__ Q,
                                                  const ushort* __restrict__ K,
                                                  const ushort* __restrict__ V,
                                                  ushort* __restrict__ O) {
  __shared__ __align__(16) ushort QP[128 * 72];
  __shared__ __align__(16) ushort Ks[64 * 64];
  __shared__ __align__(16) ushort Vt[64 * 72];
  const int pair = blockIdx.x & 127;
  const int b = pair >> 4;
  const int h = pair & 15;
  const int qt = blockIdx.x >> 7;
  const int t = threadIdx.x;
  const int lane = t & 63;
  const int w = t >> 6;
  const int col = lane & 15;
  const int quad = lane >> 4;

  const size_t base = (size_t)b * 1024 * 1024 + h * 64;
  const int qrow0 = qt * 128;

  // stage Q (128 x 64): 32 ushorts per thread
  {
    const int row = t >> 1;
    const int c0 = (t & 1) * 32;
    const ushort* src = Q + base + (size_t)(qrow0 + row) * 1024 + c0;
    uint4 v0 = reinterpret_cast<const uint4*>(src)[0];
    uint4 v1 = reinterpret_cast<const uint4*>(src)[1];
    uint4 v2 = reinterpret_cast<const uint4*>(src)[2];
    uint4 v3 = reinterpret_cast<const uint4*>(src)[3];
    reinterpret_cast<uint4*>(&QP[row * 72 + c0])[0] = v0;
    reinterpret_cast<uint4*>(&QP[row * 72 + c0])[1] = v1;
    reinterpret_cast<uint4*>(&QP[row * 72 + c0])[2] = v2;
    reinterpret_cast<uint4*>(&QP[row * 72 + c0])[3] = v3;
  }
  __syncthreads();
  bf16x8 qa[2][2];
#pragma unroll
  for (int g = 0; g < 2; ++g)
#pragma unroll
    for (int half = 0; half < 2; ++half)
      qa[g][half] =
          ld8(&QP[(w * 32 + g * 16 + col) * 72 + half * 32 + quad * 8]);
  // qa reads complete before the first kt staging barrier -> reusing QP as
  // the P buffer afterwards is race-free.

  f32x4 o_[2][4];
#pragma unroll
  for (int g = 0; g < 2; ++g)
#pragma unroll
    for (int c = 0; c < 4; ++c) o_[g][c] = (f32x4){0.f, 0.f, 0.f, 0.f};
  float m_s[2] = {-1e30f, -1e30f};
  float l_s[2] = {0.f, 0.f};

  // K staging geometry (swizzled gld16): wave w covers rows w*16..w*16+15
  const int krow = w * 16 + (lane >> 3);
  const int kcs = (((lane & 7) ^ (lane >> 3)) << 3);  // swizzled ushort col
  const int s7 = col & 7;

  for (int kt = 0; kt < 16; ++kt) {
    // stage K via DMA (swizzled source) and V transposed (reg path)
    {
      const ushort* k0 = K + base + (size_t)(kt * 64 + krow) * 1024 + kcs;
      gld16(k0, &Ks[(w * 16) * 64]);
      gld16(k0 + 8 * 1024, &Ks[(w * 16 + 8) * 64]);
      const int vs = t & 63;
      const int ve = (t >> 6) * 16;
      const ushort* vsrc = V + base + (size_t)(kt * 64 + vs) * 1024 + ve;
      union { uint4 u[2]; ushort s[16]; } vv;
      vv.u[0] = reinterpret_cast<const uint4*>(vsrc)[0];
      vv.u[1] = reinterpret_cast<const uint4*>(vsrc)[1];
#pragma unroll
      for (int j = 0; j < 16; ++j) Vt[(ve + j) * 72 + vs] = vv.s[j];
    }
    __syncthreads();

    // S^T = K Q^T; sc[g][c][r] = S[q=lane&15(+g*16+w*32)][k=c*16+quad*4+r]
    f32x4 sc[2][4];
#pragma unroll
    for (int c = 0; c < 4; ++c) {
      const int R = (c * 16 + col) * 64;
      bf16x8 kb0 = ld8(&Ks[R + ((quad ^ s7) << 3)]);
      bf16x8 kb1 = ld8(&Ks[R + (((quad + 4) ^ s7) << 3)]);
#pragma unroll
      for (int g = 0; g < 2; ++g) {
        f32x4 z = {0.f, 0.f, 0.f, 0.f};
        z = __builtin_amdgcn_mfma_f32_16x16x32_bf16(kb0, qa[g][0], z, 0, 0, 0);
        z = __builtin_amdgcn_mfma_f32_16x16x32_bf16(kb1, qa[g][1], z, 0, 0, 0);
        sc[g][c] = z;
      }
    }

    // online softmax, row-local, with defer-max (THR=8)
    float al[2];
    bool df[2];
#pragma unroll
    for (int g = 0; g < 2; ++g) {
      float mx = sc[g][0][0];
#pragma unroll
      for (int c = 0; c < 4; ++c)
#pragma unroll
        for (int r = 0; r < 4; ++r) mx = fmaxf(mx, sc[g][c][r]);
      mx = fmaxf(mx, __shfl_xor(mx, 16));
      mx = fmaxf(mx, __shfl_xor(mx, 32));
      df[g] = __all(mx - m_s[g] <= 8.0f) != 0;
      if (df[g]) {
        al[g] = 1.0f;
      } else {
        const float m_new = fmaxf(m_s[g], mx);
        al[g] = __expf(m_s[g] - m_new);
        m_s[g] = m_new;
      }
      float rs = 0.f;
      const int prow = (w * 32 + g * 16 + col) * 72;
#pragma unroll
      for (int c = 0; c < 4; ++c) {
        const float p0 = __expf(sc[g][c][0] - m_s[g]);
        const float p1 = __expf(sc[g][c][1] - m_s[g]);
        const float p2 = __expf(sc[g][c][2] - m_s[g]);
        const float p3 = __expf(sc[g][c][3] - m_s[g]);
        rs += (p0 + p1) + (p2 + p3);
        union { uint2 u; ushort s[4]; } pk;
        pk.s[0] = f2bf(p0);
        pk.s[1] = f2bf(p1);
        pk.s[2] = f2bf(p2);
        pk.s[3] = f2bf(p3);
        *reinterpret_cast<uint2*>(&QP[prow + c * 16 + quad * 4]) = pk.u;
      }
      rs += __shfl_xor(rs, 16);
      rs += __shfl_xor(rs, 32);
      l_s[g] = df[g] ? (l_s[g] + rs) : (l_s[g] * al[g] + rs);
    }

    // rescale O with per-row alpha (skipped entirely when deferred)
#pragma unroll
    for (int g = 0; g < 2; ++g)
      if (!df[g]) {
#pragma unroll
        for (int r = 0; r < 4; ++r) {
          const float a = __shfl(al[g], (lane & 48) | (quad * 4 + r));
          o_[g][0][r] *= a;
          o_[g][1][r] *= a;
          o_[g][2][r] *= a;
          o_[g][3][r] *= a;
        }
      }

    // O += P V (own-wave P rows; no barrier needed before reads)
    bf16x8 pa[2][2];
#pragma unroll
    for (int g = 0; g < 2; ++g)
#pragma unroll
      for (int half = 0; half < 2; ++half)
        pa[g][half] =
            ld8(&QP[(w * 32 + g * 16 + col) * 72 + half * 32 + quad * 8]);
#pragma unroll
    for (int c = 0; c < 4; ++c) {
      bf16x8 vb0 = ld8(&Vt[(c * 16 + col) * 72 + quad * 8]);
      bf16x8 vb1 = ld8(&Vt[(c * 16 + col) * 72 + 32 + quad * 8]);
#pragma unroll
      for (int g = 0; g < 2; ++g) {
        o_[g][c] = __builtin_amdgcn_mfma_f32_16x16x32_bf16(pa[g][0], vb0,
                                                           o_[g][c], 0, 0, 0);
        o_[g][c] = __builtin_amdgcn_mfma_f32_16x16x32_bf16(pa[g][1], vb1,
                                                           o_[g][c], 0, 0, 0);
      }
    }
    __syncthreads();
  }

#pragma unroll
  for (int g = 0; g < 2; ++g)
#pragma unroll
    for (int r = 0; r < 4; ++r) {
      const float lr = __shfl(l_s[g], (lane & 48) | (quad * 4 + r));
      const float inv = 1.f / lr;
      const size_t row =
          base + (size_t)(qrow0 + w * 32 + g * 16 + quad * 4 + r) * 1024;
      O[row + 0 + col] = f2bf(o_[g][0][r] * inv);
      O[row + 16 + col] = f2bf(o_[g][1][r] * inv);
      O[row + 32 + col] = f2bf(o_[g][2][r] * inv);
      O[row + 48 + col] = f2bf(o_[g][3][r] * inv);
    }
}

// --------------------------------------------------------------------------
extern "C" void kernel_launch(void* const* d_in, const int* in_sizes, int n_in,
                              void* d_out, int out_size, void* d_ws, size_t ws_size,
                              hipStream_t stream) {
  const float* q = (const float*)d_in[0];
  const float* k = (const float*)d_in[1];
  const float* v = (const float*)d_in[2];
  const float* Wq = (const float*)d_in[3];
  const float* Wk = (const float*)d_in[4];
  const float* Wv = (const float*)d_in[5];
  const float* Wo = (const float*)d_in[6];
  const float* bo = (const float*)d_in[7];
  float* out = (float*)d_out;
  ushort* ws = (ushort*)d_ws;

  const size_t M8 = 8u << 20;  // 8M bf16 = 16 MB
  const size_t M1 = 1u << 20;
  ushort* Qp = ws;                 // also flash output (in-place)
  ushort* Kp = ws + M8;
  ushort* Vp = ws + 2 * M8;
  ushort* WqT = ws + 3 * M8;
  ushort* WkT = WqT + M1;
  ushort* WvT = WkT + M1;
  ushort* WoB = WvT + M1;          // total 56 MB

  // d_out (32 MB fp32) as bf16 scratch: q~ at 0, k~ at +16MB.
  ushort* X0 = (ushort*)d_out;
  ushort* X1 = X0 + M8;

  prep_wt3<<<768, 256, 0, stream>>>(Wq, Wk, Wv, WqT, WkT, WvT);
  cvt3<<<4352, 256, 0, stream>>>(q, X0, k, X1, Wo, WoB);
  // attn scale folded into Q projection (exact: 2^-5 exponent shift in bf16)
  gemm_proj3<<<1536, 256, 0, stream>>>(X0, WqT, Qp, X1, WkT, Kp, v, WvT, Vp);

  flash_attn<<<1024, 256, 0, stream>>>(Qp, Kp, Vp, Qp);

  gemm_out<<<512, 256, 0, stream>>>(Qp, WoB, bo, out);
}

// Round 6
// 341.610 us; speedup vs baseline: 1.1253x; 1.0316x over previous
//
#include <hip/hip_runtime.h>
#include <stdint.h>

// ---------------------------------------------------------------------------
// MultiHeadAttention: B=8 S=1024 QKV=1024 H=16 E=64 OUT=1024.
// fp32 in / fp32 out, bf16 MFMA internals, fp32 accum.
// R13: counted-vmcnt double-buffered GEMM K-loop (T4) for the bf16-A GEMMs.
//   R12 counters: proj3 latency-bound (all pipes <22%, FETCH already ideal).
//   New core_bb_pipe: 2 LDS buffers, per K-step:
//     stage8(next->other buf)           // 8 global_load_lds stay IN FLIGHT
//     s_waitcnt vmcnt(8)                // wait ONLY previous tile's loads
//     s_barrier                         // raw: no forced drain
//     ds_read + 32 MFMA
//     s_waitcnt lgkmcnt(0); s_barrier   // reads retired before buf reuse
//   Buffers alternate statically (two steps per loop body). R10's failure
//   (__syncthreads full drain before ds_reads) avoided via explicit asm.
//   v-third keeps single-buffer core_f32a (fp32 reg loads share vmcnt ->
//   counting would be wrong). flash unchanged (control).
// R12 kept: XCD-chunked 1D decode (id=64a+8bx+b -> A fetched once, 57MB).
// flash MFMA maps (HW-verified m89/m91):
//   A[m=lane&15][k=quad*8+j], B[k=quad*8+j][n=lane&15], D[row=quad*4+r][col]
// ws: [Qp 16][Kp 16][Vp 16][WqT 2|WkT 2|WvT 2|WoB 2] = 56 MB.
// d_out doubles as bf16 scratch (q~ at 0, k~ at 16MB).
// ---------------------------------------------------------------------------

typedef __bf16 bf16x8 __attribute__((ext_vector_type(8)));
typedef float f32x4 __attribute__((ext_vector_type(4)));

typedef __attribute__((address_space(3))) uint32_t lds_u32;
typedef const __attribute__((address_space(1))) uint32_t glb_u32;

__device__ __forceinline__ ushort f2bf(float f) {
  uint32_t x = __float_as_uint(f);
  x += 0x7fff + ((x >> 16) & 1);  // RNE
  return (ushort)(x >> 16);
}
__device__ __forceinline__ bf16x8 ld8(const ushort* p) {
  union { uint4 u; bf16x8 b; } c;
  c.u = *reinterpret_cast<const uint4*>(p);
  return c.b;
}
__device__ __forceinline__ void cvt16(const float* __restrict__ src,
                                      ushort* __restrict__ dst) {
  union { uint4 u[2]; ushort s[16]; } o;
#pragma unroll
  for (int i = 0; i < 4; ++i) {
    const float4 f = reinterpret_cast<const float4*>(src)[i];
    o.s[4 * i + 0] = f2bf(f.x);
    o.s[4 * i + 1] = f2bf(f.y);
    o.s[4 * i + 2] = f2bf(f.z);
    o.s[4 * i + 3] = f2bf(f.w);
  }
  reinterpret_cast<uint4*>(dst)[0] = o.u[0];
  reinterpret_cast<uint4*>(dst)[1] = o.u[1];
}

// global->LDS DMA, 16B/lane. LDS dest wave-uniform base + lane*16 (m104/m108).
__device__ __forceinline__ void gld16(const ushort* g, ushort* l) {
  __builtin_amdgcn_global_load_lds((glb_u32*)g, (lds_u32*)l, 16, 0, 0);
}

// --------------------------------------------------------------------------
// W[16][1024][64] fp32 -> WT[1024][1024] bf16 (WT[n=h*64+e][k]).
// 3 weights in one launch: grid 768 (bid>>8 selects W). 256 thr.
// --------------------------------------------------------------------------
__global__ __launch_bounds__(256) void prep_wt3(
    const float* __restrict__ W0, const float* __restrict__ W1,
    const float* __restrict__ W2, ushort* __restrict__ T0,
    ushort* __restrict__ T1, ushort* __restrict__ T2) {
  __shared__ __align__(16) ushort tile[64 * 72];
  const int sel = blockIdx.x >> 8;
  const float* W = sel == 0 ? W0 : sel == 1 ? W1 : W2;
  ushort* WT = sel == 0 ? T0 : sel == 1 ? T1 : T2;
  const int bid = blockIdx.x & 255;
  const int h = bid >> 4;
  const int kt = bid & 15;
  const int t = threadIdx.x;
  const int row = t >> 2;
  const int ch = (t & 3) * 16;
  cvt16(W + ((size_t)h * 1024 + kt * 64 + row) * 64 + ch, &tile[row * 72 + ch]);
  __syncthreads();
  const int e = t >> 2;
  const int kc = (t & 3) * 16;
  ushort vals[16];
#pragma unroll
  for (int j = 0; j < 16; ++j) vals[j] = tile[(kc + j) * 72 + e];
  ushort* dst = WT + (size_t)(h * 64 + e) * 1024 + kt * 64 + kc;
  reinterpret_cast<uint4*>(dst)[0] = *reinterpret_cast<uint4*>(&vals[0]);
  reinterpret_cast<uint4*>(dst)[1] = *reinterpret_cast<uint4*>(&vals[8]);
}

// q (8M) + k (8M) + Wo (1M) fp32->bf16 in one launch. grid 4352.
__global__ __launch_bounds__(256) void cvt3(const float* __restrict__ s0,
                                            ushort* __restrict__ d0,
                                            const float* __restrict__ s1,
                                            ushort* __restrict__ d1,
                                            const float* __restrict__ s2,
                                            ushort* __restrict__ d2) {
  int b = blockIdx.x;
  const float* s;
  ushort* d;
  if (b < 2048) { s = s0; d = d0; }
  else if (b < 4096) { s = s1; d = d1; b -= 2048; }
  else { s = s2; d = d2; b -= 4096; }
  const int i = (b * 256 + threadIdx.x) * 16;
  cvt16(s + i, d + i);
}

// --------------------------------------------------------------------------
// Pipelined GEMM core (bf16 A): counted-vmcnt double-buffer.
// 128x128 tile, BK=64, 4 waves 2x2. Buffers A0/A1/B0/B1 each 128x64 (16KB).
// Per step: stage next (other buf) -> vmcnt(8) -> barrier -> compute ->
// lgkmcnt(0) -> barrier. Loads stay in flight across barriers (T4).
// --------------------------------------------------------------------------
__device__ __forceinline__ void stage8(const ushort* a_src, const ushort* b_src,
                                       ushort* as, ushort* bs, int w, int k0) {
#pragma unroll
  for (int c = 0; c < 4; ++c) {
    gld16(a_src + (size_t)c * 32 * 1024 + k0, as + (w * 8 + c * 32) * 64);
    gld16(b_src + (size_t)c * 32 * 1024 + k0, bs + (w * 8 + c * 32) * 64);
  }
}

template <bool F32OUT>
__device__ __forceinline__ void core_bb_pipe(ushort* __restrict__ S,
                                             const ushort* __restrict__ A,
                                             const ushort* __restrict__ Bt,
                                             const float* __restrict__ bias,
                                             void* __restrict__ Cv,
                                             float oscale, int bx, int by) {
  ushort* A0 = S;                  // 4 x 16KB buffers
  ushort* B0 = S + 128 * 64;
  ushort* A1 = S + 2 * 128 * 64;
  ushort* B1 = S + 3 * 128 * 64;
  const int n0 = bx * 128;
  const int m0 = by * 128;
  const int t = threadIdx.x;
  const int lane = t & 63;
  const int w = t >> 6;
  const int wm = w >> 1, wn = w & 1;
  const int col = lane & 15;
  const int quad = lane >> 4;
  const int gr = lane >> 3;        // 0..7
  const int gc = (lane & 7) * 8;   // ushort col 0..56

  f32x4 acc[4][4];
#pragma unroll
  for (int i = 0; i < 4; ++i)
#pragma unroll
    for (int j = 0; j < 4; ++j) acc[i][j] = (f32x4){0.f, 0.f, 0.f, 0.f};

  const ushort* a_src = A + (size_t)(m0 + w * 8 + gr) * 1024 + gc;
  const ushort* b_src = Bt + (size_t)(n0 + w * 8 + gr) * 1024 + gc;

  auto compute = [&](const ushort* asb, const ushort* bsb) {
#pragma unroll
    for (int half = 0; half < 2; ++half) {
      bf16x8 af[4], bfr[4];
#pragma unroll
      for (int i = 0; i < 4; ++i)
        af[i] = ld8(&asb[(wm * 64 + i * 16 + col) * 64 + half * 32 + quad * 8]);
#pragma unroll
      for (int j = 0; j < 4; ++j)
        bfr[j] = ld8(&bsb[(wn * 64 + j * 16 + col) * 64 + half * 32 + quad * 8]);
#pragma unroll
      for (int i = 0; i < 4; ++i)
#pragma unroll
        for (int j = 0; j < 4; ++j)
          acc[i][j] = __builtin_amdgcn_mfma_f32_16x16x32_bf16(af[i], bfr[j],
                                                              acc[i][j], 0, 0, 0);
    }
  };

  // prologue: tile 0 -> buf0 (8 loads in flight)
  stage8(a_src, b_src, A0, B0, w, 0);

  for (int t2 = 0; t2 < 16; t2 += 2) {
    // even step: read buf0, stage t2+1 -> buf1 (t2+1 <= 15 always)
    stage8(a_src, b_src, A1, B1, w, (t2 + 1) * 64);
    asm volatile("s_waitcnt vmcnt(8)" ::: "memory");  // prev tile landed
    __builtin_amdgcn_sched_barrier(0);
    __builtin_amdgcn_s_barrier();
    __builtin_amdgcn_sched_barrier(0);
    compute(A0, B0);
    asm volatile("s_waitcnt lgkmcnt(0)" ::: "memory");  // my reads retired
    __builtin_amdgcn_sched_barrier(0);
    __builtin_amdgcn_s_barrier();

    // odd step: read buf1, stage t2+2 -> buf0 (skip on last)
    if (t2 < 14) {
      stage8(a_src, b_src, A0, B0, w, (t2 + 2) * 64);
      asm volatile("s_waitcnt vmcnt(8)" ::: "memory");
    } else {
      asm volatile("s_waitcnt vmcnt(0)" ::: "memory");
    }
    __builtin_amdgcn_sched_barrier(0);
    __builtin_amdgcn_s_barrier();
    __builtin_amdgcn_sched_barrier(0);
    compute(A1, B1);
    asm volatile("s_waitcnt lgkmcnt(0)" ::: "memory");
    __builtin_amdgcn_sched_barrier(0);
    __builtin_amdgcn_s_barrier();
  }

#pragma unroll
  for (int i = 0; i < 4; ++i)
#pragma unroll
    for (int j = 0; j < 4; ++j) {
      const int n = n0 + wn * 64 + j * 16 + col;
      float bv = 0.f;
      if (F32OUT) bv = bias[n];
#pragma unroll
      for (int r = 0; r < 4; ++r) {
        const int m = m0 + wm * 64 + i * 16 + quad * 4 + r;
        if (F32OUT)
          reinterpret_cast<float*>(Cv)[(size_t)m * 1024 + n] = acc[i][j][r] + bv;
        else
          reinterpret_cast<ushort*>(Cv)[(size_t)m * 1024 + n] =
              f2bf(acc[i][j][r] * oscale);
      }
    }
}

// --------------------------------------------------------------------------
// GEMM core (fp32 A, in-kernel cvt): A staged via cvt16 into stride-72 LDS
// (R7-verified layout), B via gld16. Single-buffer (mixed vmcnt population
// makes counted waits unsafe here). Uses S[0..17408).
// --------------------------------------------------------------------------
__device__ __forceinline__ void core_f32a(ushort* __restrict__ S,
                                          const float* __restrict__ A,
                                          const ushort* __restrict__ Bt,
                                          ushort* __restrict__ C, int bx,
                                          int by) {
  ushort* As72 = S;                 // 128*72
  ushort* Bs = S + 128 * 72;        // 128*64
  const int n0 = bx * 128;
  const int m0 = by * 128;
  const int t = threadIdx.x;
  const int lane = t & 63;
  const int w = t >> 6;
  const int wm = w >> 1, wn = w & 1;
  const int col = lane & 15;
  const int quad = lane >> 4;
  const int gr = lane >> 3;
  const int gc = (lane & 7) * 8;
  const int srow = t >> 1;        // 0..127
  const int sc0 = (t & 1) * 32;   // 0 or 32

  f32x4 acc[4][4];
#pragma unroll
  for (int i = 0; i < 4; ++i)
#pragma unroll
    for (int j = 0; j < 4; ++j) acc[i][j] = (f32x4){0.f, 0.f, 0.f, 0.f};

  const float* a_src = A + (size_t)(m0 + srow) * 1024 + sc0;
  const ushort* b_src = Bt + (size_t)(n0 + w * 8 + gr) * 1024 + gc;
  ushort* bs_base = &Bs[(w * 8) * 64];

  for (int k0 = 0; k0 < 1024; k0 += 64) {
#pragma unroll
    for (int c = 0; c < 4; ++c)
      gld16(b_src + (size_t)c * 32 * 1024 + k0, bs_base + c * 32 * 64);
    cvt16(a_src + k0, &As72[srow * 72 + sc0]);
    cvt16(a_src + k0 + 16, &As72[srow * 72 + sc0 + 16]);
    __syncthreads();

#pragma unroll
    for (int half = 0; half < 2; ++half) {
      bf16x8 af[4], bfr[4];
#pragma unroll
      for (int i = 0; i < 4; ++i)
        af[i] = ld8(&As72[(wm * 64 + i * 16 + col) * 72 + half * 32 + quad * 8]);
#pragma unroll
      for (int j = 0; j < 4; ++j)
        bfr[j] = ld8(&Bs[(wn * 64 + j * 16 + col) * 64 + half * 32 + quad * 8]);
#pragma unroll
      for (int i = 0; i < 4; ++i)
#pragma unroll
        for (int j = 0; j < 4; ++j)
          acc[i][j] = __builtin_amdgcn_mfma_f32_16x16x32_bf16(af[i], bfr[j],
                                                              acc[i][j], 0, 0, 0);
    }
    __syncthreads();
  }

#pragma unroll
  for (int i = 0; i < 4; ++i)
#pragma unroll
    for (int j = 0; j < 4; ++j) {
      const int n = n0 + wn * 64 + j * 16 + col;
#pragma unroll
      for (int r = 0; r < 4; ++r) {
        const int m = m0 + wm * 64 + i * 16 + quad * 4 + r;
        C[(size_t)m * 1024 + n] = f2bf(acc[i][j][r]);
      }
    }
}

// OUT gemm: C fp32 + bias. grid 512 (1D, XCD-chunked decode).
__global__ __launch_bounds__(256) void gemm_out(const ushort* __restrict__ A,
                                                const ushort* __restrict__ Bt,
                                                const float* __restrict__ bias,
                                                float* __restrict__ C) {
  __shared__ __align__(16) ushort S[4 * 128 * 64];
  const int id = blockIdx.x;
  const int bx = (id >> 3) & 7;
  const int by = ((id >> 6) << 3) | (id & 7);
  core_bb_pipe<true>(S, A, Bt, bias, C, 1.0f, bx, by);
}

// All three projections in one launch. grid 1536 (1D, XCD-chunked decode).
// id = 64*a + 8*bx + b; by = 8*a + b (0..191). by<64: q (scale 2^-5 folded);
// <128: k; else: v (fp32 A, single-buffer path).
__global__ __launch_bounds__(256) void gemm_proj3(
    const ushort* __restrict__ Aq, const ushort* __restrict__ Bq,
    ushort* __restrict__ Cq, const ushort* __restrict__ Ak,
    const ushort* __restrict__ Bk, ushort* __restrict__ Ck,
    const float* __restrict__ Av, const ushort* __restrict__ Bv,
    ushort* __restrict__ Cvp) {
  __shared__ __align__(16) ushort S[4 * 128 * 64];  // 64KB shared pool
  const int id = blockIdx.x;
  const int bx = (id >> 3) & 7;
  const int by = ((id >> 6) << 3) | (id & 7);
  if (by < 64)
    core_bb_pipe<false>(S, Aq, Bq, nullptr, Cq, 0.03125f, bx, by);
  else if (by < 128)
    core_bb_pipe<false>(S, Ak, Bk, nullptr, Ck, 1.0f, bx, by - 64);
  else
    core_f32a(S, Av, Bv, Cvp, bx, by - 128);
}

// --------------------------------------------------------------------------
// Flash attention, 128-row q-tiles. Q,K,V,O bf16 [8192][1024], O aliases Q.
// Q PRE-SCALED by 1/sqrt(1024). grid 1024; block 256 (4 waves); wave w owns
// q-rows w*32..+31. Swapped QK^T (lane-local softmax rows). K staged via
// gld16 + granule XOR swizzle into linear Ks[64][64]. Defer-max (THR=8).
// Barriers: 2/kt. LDS 35 KB. UNCHANGED from R11 (control).
// --------------------------------------------------------------------------
__global__ __launch_bounds__(256) void flash_attn(const ushort* __restrict__ Q,
                                                  const ushort* __restrict__ K,
                                                  const ushort* __restrict__ V,
                                                  ushort* __restrict__ O) {
  __shared__ __align__(16) ushort QP[128 * 72];
  __shared__ __align__(16) ushort Ks[64 * 64];
  __shared__ __align__(16) ushort Vt[64 * 72];
  const int pair = blockIdx.x & 127;
  const int b = pair >> 4;
  const int h = pair & 15;
  const int qt = blockIdx.x >> 7;
  const int t = threadIdx.x;
  const int lane = t & 63;
  const int w = t >> 6;
  const int col = lane & 15;
  const int quad = lane >> 4;

  const size_t base = (size_t)b * 1024 * 1024 + h * 64;
  const int qrow0 = qt * 128;

  // stage Q (128 x 64): 32 ushorts per thread
  {
    const int row = t >> 1;
    const int c0 = (t & 1) * 32;
    const ushort* src = Q + base + (size_t)(qrow0 + row) * 1024 + c0;
    uint4 v0 = reinterpret_cast<const uint4*>(src)[0];
    uint4 v1 = reinterpret_cast<const uint4*>(src)[1];
    uint4 v2 = reinterpret_cast<const uint4*>(src)[2];
    uint4 v3 = reinterpret_cast<const uint4*>(src)[3];
    reinterpret_cast<uint4*>(&QP[row * 72 + c0])[0] = v0;
    reinterpret_cast<uint4*>(&QP[row * 72 + c0])[1] = v1;
    reinterpret_cast<uint4*>(&QP[row * 72 + c0])[2] = v2;
    reinterpret_cast<uint4*>(&QP[row * 72 + c0])[3] = v3;
  }
  __syncthreads();
  bf16x8 qa[2][2];
#pragma unroll
  for (int g = 0; g < 2; ++g)
#pragma unroll
    for (int half = 0; half < 2; ++half)
      qa[g][half] =
          ld8(&QP[(w * 32 + g * 16 + col) * 72 + half * 32 + quad * 8]);
  // qa reads complete before the first kt staging barrier -> reusing QP as
  // the P buffer afterwards is race-free.

  f32x4 o_[2][4];
#pragma unroll
  for (int g = 0; g < 2; ++g)
#pragma unroll
    for (int c = 0; c < 4; ++c) o_[g][c] = (f32x4){0.f, 0.f, 0.f, 0.f};
  float m_s[2] = {-1e30f, -1e30f};
  float l_s[2] = {0.f, 0.f};

  // K staging geometry (swizzled gld16): wave w covers rows w*16..w*16+15
  const int krow = w * 16 + (lane >> 3);
  const int kcs = (((lane & 7) ^ (lane >> 3)) << 3);  // swizzled ushort col
  const int s7 = col & 7;

  for (int kt = 0; kt < 16; ++kt) {
    // stage K via DMA (swizzled source) and V transposed (reg path)
    {
      const ushort* k0 = K + base + (size_t)(kt * 64 + krow) * 1024 + kcs;
      gld16(k0, &Ks[(w * 16) * 64]);
      gld16(k0 + 8 * 1024, &Ks[(w * 16 + 8) * 64]);
      const int vs = t & 63;
      const int ve = (t >> 6) * 16;
      const ushort* vsrc = V + base + (size_t)(kt * 64 + vs) * 1024 + ve;
      union { uint4 u[2]; ushort s[16]; } vv;
      vv.u[0] = reinterpret_cast<const uint4*>(vsrc)[0];
      vv.u[1] = reinterpret_cast<const uint4*>(vsrc)[1];
#pragma unroll
      for (int j = 0; j < 16; ++j) Vt[(ve + j) * 72 + vs] = vv.s[j];
    }
    __syncthreads();

    // S^T = K Q^T; sc[g][c][r] = S[q=lane&15(+g*16+w*32)][k=c*16+quad*4+r]
    f32x4 sc[2][4];
#pragma unroll
    for (int c = 0; c < 4; ++c) {
      const int R = (c * 16 + col) * 64;
      bf16x8 kb0 = ld8(&Ks[R + ((quad ^ s7) << 3)]);
      bf16x8 kb1 = ld8(&Ks[R + (((quad + 4) ^ s7) << 3)]);
#pragma unroll
      for (int g = 0; g < 2; ++g) {
        f32x4 z = {0.f, 0.f, 0.f, 0.f};
        z = __builtin_amdgcn_mfma_f32_16x16x32_bf16(kb0, qa[g][0], z, 0, 0, 0);
        z = __builtin_amdgcn_mfma_f32_16x16x32_bf16(kb1, qa[g][1], z, 0, 0, 0);
        sc[g][c] = z;
      }
    }

    // online softmax, row-local, with defer-max (THR=8)
    float al[2];
    bool df[2];
#pragma unroll
    for (int g = 0; g < 2; ++g) {
      float mx = sc[g][0][0];
#pragma unroll
      for (int c = 0; c < 4; ++c)
#pragma unroll
        for (int r = 0; r < 4; ++r) mx = fmaxf(mx, sc[g][c][r]);
      mx = fmaxf(mx, __shfl_xor(mx, 16));
      mx = fmaxf(mx, __shfl_xor(mx, 32));
      df[g] = __all(mx - m_s[g] <= 8.0f) != 0;
      if (df[g]) {
        al[g] = 1.0f;
      } else {
        const float m_new = fmaxf(m_s[g], mx);
        al[g] = __expf(m_s[g] - m_new);
        m_s[g] = m_new;
      }
      float rs = 0.f;
      const int prow = (w * 32 + g * 16 + col) * 72;
#pragma unroll
      for (int c = 0; c < 4; ++c) {
        const float p0 = __expf(sc[g][c][0] - m_s[g]);
        const float p1 = __expf(sc[g][c][1] - m_s[g]);
        const float p2 = __expf(sc[g][c][2] - m_s[g]);
        const float p3 = __expf(sc[g][c][3] - m_s[g]);
        rs += (p0 + p1) + (p2 + p3);
        union { uint2 u; ushort s[4]; } pk;
        pk.s[0] = f2bf(p0);
        pk.s[1] = f2bf(p1);
        pk.s[2] = f2bf(p2);
        pk.s[3] = f2bf(p3);
        *reinterpret_cast<uint2*>(&QP[prow + c * 16 + quad * 4]) = pk.u;
      }
      rs += __shfl_xor(rs, 16);
      rs += __shfl_xor(rs, 32);
      l_s[g] = df[g] ? (l_s[g] + rs) : (l_s[g] * al[g] + rs);
    }

    // rescale O with per-row alpha (skipped entirely when deferred)
#pragma unroll
    for (int g = 0; g < 2; ++g)
      if (!df[g]) {
#pragma unroll
        for (int r = 0; r < 4; ++r) {
          const float a = __shfl(al[g], (lane & 48) | (quad * 4 + r));
          o_[g][0][r] *= a;
          o_[g][1][r] *= a;
          o_[g][2][r] *= a;
          o_[g][3][r] *= a;
        }
      }

    // O += P V (own-wave P rows; no barrier needed before reads)
    bf16x8 pa[2][2];
#pragma unroll
    for (int g = 0; g < 2; ++g)
#pragma unroll
      for (int half = 0; half < 2; ++half)
        pa[g][half] =
            ld8(&QP[(w * 32 + g * 16 + col) * 72 + half * 32 + quad * 8]);
#pragma unroll
    for (int c = 0; c < 4; ++c) {
      bf16x8 vb0 = ld8(&Vt[(c * 16 + col) * 72 + quad * 8]);
      bf16x8 vb1 = ld8(&Vt[(c * 16 + col) * 72 + 32 + quad * 8]);
#pragma unroll
      for (int g = 0; g < 2; ++g) {
        o_[g][c] = __builtin_amdgcn_mfma_f32_16x16x32_bf16(pa[g][0], vb0,
                                                           o_[g][c], 0, 0, 0);
        o_[g][c] = __builtin_amdgcn_mfma_f32_16x16x32_bf16(pa[g][1], vb1,
                                                           o_[g][c], 0, 0, 0);
      }
    }
    __syncthreads();
  }

#pragma unroll
  for (int g = 0; g < 2; ++g)
#pragma unroll
    for (int r = 0; r < 4; ++r) {
      const float lr = __shfl(l_s[g], (lane & 48) | (quad * 4 + r));
      const float inv = 1.f / lr;
      const size_t row =
          base + (size_t)(qrow0 + w * 32 + g * 16 + quad * 4 + r) * 1024;
      O[row + 0 + col] = f2bf(o_[g][0][r] * inv);
      O[row + 16 + col] = f2bf(o_[g][1][r] * inv);
      O[row + 32 + col] = f2bf(o_[g][2][r] * inv);
      O[row + 48 + col] = f2bf(o_[g][3][r] * inv);
    }
}

// --------------------------------------------------------------------------
extern "C" void kernel_launch(void* const* d_in, const int* in_sizes, int n_in,
                              void* d_out, int out_size, void* d_ws, size_t ws_size,
                              hipStream_t stream) {
  const float* q = (const float*)d_in[0];
  const float* k = (const float*)d_in[1];
  const float* v = (const float*)d_in[2];
  const float* Wq = (const float*)d_in[3];
  const float* Wk = (const float*)d_in[4];
  const float* Wv = (const float*)d_in[5];
  const float* Wo = (const float*)d_in[6];
  const float* bo = (const float*)d_in[7];
  float* out = (float*)d_out;
  ushort* ws = (ushort*)d_ws;

  const size_t M8 = 8u << 20;  // 8M bf16 = 16 MB
  const size_t M1 = 1u << 20;
  ushort* Qp = ws;                 // also flash output (in-place)
  ushort* Kp = ws + M8;
  ushort* Vp = ws + 2 * M8;
  ushort* WqT = ws + 3 * M8;
  ushort* WkT = WqT + M1;
  ushort* WvT = WkT + M1;
  ushort* WoB = WvT + M1;          // total 56 MB

  // d_out (32 MB fp32) as bf16 scratch: q~ at 0, k~ at +16MB.
  ushort* X0 = (ushort*)d_out;
  ushort* X1 = X0 + M8;

  prep_wt3<<<768, 256, 0, stream>>>(Wq, Wk, Wv, WqT, WkT, WvT);
  cvt3<<<4352, 256, 0, stream>>>(q, X0, k, X1, Wo, WoB);
  // attn scale folded into Q projection (exact: 2^-5 exponent shift in bf16)
  gemm_proj3<<<1536, 256, 0, stream>>>(X0, WqT, Qp, X1, WkT, Kp, v, WvT, Vp);

  flash_attn<<<1024, 256, 0, stream>>>(Qp, Kp, Vp, Qp);

  gemm_out<<<512, 256, 0, stream>>>(Qp, WoB, bo, out);
}

// Round 7
// 328.238 us; speedup vs baseline: 1.1711x; 1.0407x over previous
//
#include <hip/hip_runtime.h>
#include <stdint.h>

// ---------------------------------------------------------------------------
// MultiHeadAttention: B=8 S=1024 QKV=1024 H=16 E=64 OUT=1024.
// fp32 in / fp32 out, bf16 MFMA internals, fp32 accum.
// R14: T2 granule-XOR swizzle on the pipelined GEMM LDS (both-sides form,
//   rule 21). R13 counters: SQ_LDS_BANK_CONFLICT=16.78M (m98 signature of
//   linear [128][64] tiles; 25% of cycles). With R13's counted-vmcnt the
//   stage stall is amortized -> LDS read is the critical path -> T2 is live
//   (m252 regime gate). Scheme (same as verified flash-K path):
//     stage: lane fetches GLOBAL granule (lane&7)^(lane>>3) of its row,
//            LDS stays linear (gld16 dest = base + lane*16).
//     read:  granule g of row R lives at LDS granule g^(R&7); R&7==col&7.
//   Applied to core_bb_pipe A+B and core_f32a B. flash unchanged (control).
// R13 kept: counted-vmcnt dbuf (stage8 -> vmcnt(8) -> s_barrier -> MFMA ->
//   lgkmcnt(0) -> s_barrier). R12 kept: XCD-chunked 1D decode.
// flash MFMA maps (HW-verified m89/m91):
//   A[m=lane&15][k=quad*8+j], B[k=quad*8+j][n=lane&15], D[row=quad*4+r][col]
// ws: [Qp 16][Kp 16][Vp 16][WqT 2|WkT 2|WvT 2|WoB 2] = 56 MB.
// d_out doubles as bf16 scratch (q~ at 0, k~ at 16MB).
// ---------------------------------------------------------------------------

typedef __bf16 bf16x8 __attribute__((ext_vector_type(8)));
typedef float f32x4 __attribute__((ext_vector_type(4)));

typedef __attribute__((address_space(3))) uint32_t lds_u32;
typedef const __attribute__((address_space(1))) uint32_t glb_u32;

__device__ __forceinline__ ushort f2bf(float f) {
  uint32_t x = __float_as_uint(f);
  x += 0x7fff + ((x >> 16) & 1);  // RNE
  return (ushort)(x >> 16);
}
__device__ __forceinline__ bf16x8 ld8(const ushort* p) {
  union { uint4 u; bf16x8 b; } c;
  c.u = *reinterpret_cast<const uint4*>(p);
  return c.b;
}
__device__ __forceinline__ void cvt16(const float* __restrict__ src,
                                      ushort* __restrict__ dst) {
  union { uint4 u[2]; ushort s[16]; } o;
#pragma unroll
  for (int i = 0; i < 4; ++i) {
    const float4 f = reinterpret_cast<const float4*>(src)[i];
    o.s[4 * i + 0] = f2bf(f.x);
    o.s[4 * i + 1] = f2bf(f.y);
    o.s[4 * i + 2] = f2bf(f.z);
    o.s[4 * i + 3] = f2bf(f.w);
  }
  reinterpret_cast<uint4*>(dst)[0] = o.u[0];
  reinterpret_cast<uint4*>(dst)[1] = o.u[1];
}

// global->LDS DMA, 16B/lane. LDS dest wave-uniform base + lane*16 (m104/m108).
__device__ __forceinline__ void gld16(const ushort* g, ushort* l) {
  __builtin_amdgcn_global_load_lds((glb_u32*)g, (lds_u32*)l, 16, 0, 0);
}

// --------------------------------------------------------------------------
// W[16][1024][64] fp32 -> WT[1024][1024] bf16 (WT[n=h*64+e][k]).
// 3 weights in one launch: grid 768 (bid>>8 selects W). 256 thr.
// --------------------------------------------------------------------------
__global__ __launch_bounds__(256) void prep_wt3(
    const float* __restrict__ W0, const float* __restrict__ W1,
    const float* __restrict__ W2, ushort* __restrict__ T0,
    ushort* __restrict__ T1, ushort* __restrict__ T2) {
  __shared__ __align__(16) ushort tile[64 * 72];
  const int sel = blockIdx.x >> 8;
  const float* W = sel == 0 ? W0 : sel == 1 ? W1 : W2;
  ushort* WT = sel == 0 ? T0 : sel == 1 ? T1 : T2;
  const int bid = blockIdx.x & 255;
  const int h = bid >> 4;
  const int kt = bid & 15;
  const int t = threadIdx.x;
  const int row = t >> 2;
  const int ch = (t & 3) * 16;
  cvt16(W + ((size_t)h * 1024 + kt * 64 + row) * 64 + ch, &tile[row * 72 + ch]);
  __syncthreads();
  const int e = t >> 2;
  const int kc = (t & 3) * 16;
  ushort vals[16];
#pragma unroll
  for (int j = 0; j < 16; ++j) vals[j] = tile[(kc + j) * 72 + e];
  ushort* dst = WT + (size_t)(h * 64 + e) * 1024 + kt * 64 + kc;
  reinterpret_cast<uint4*>(dst)[0] = *reinterpret_cast<uint4*>(&vals[0]);
  reinterpret_cast<uint4*>(dst)[1] = *reinterpret_cast<uint4*>(&vals[8]);
}

// q (8M) + k (8M) + Wo (1M) fp32->bf16 in one launch. grid 4352.
__global__ __launch_bounds__(256) void cvt3(const float* __restrict__ s0,
                                            ushort* __restrict__ d0,
                                            const float* __restrict__ s1,
                                            ushort* __restrict__ d1,
                                            const float* __restrict__ s2,
                                            ushort* __restrict__ d2) {
  int b = blockIdx.x;
  const float* s;
  ushort* d;
  if (b < 2048) { s = s0; d = d0; }
  else if (b < 4096) { s = s1; d = d1; b -= 2048; }
  else { s = s2; d = d2; b -= 4096; }
  const int i = (b * 256 + threadIdx.x) * 16;
  cvt16(s + i, d + i);
}

// --------------------------------------------------------------------------
// Pipelined GEMM core (bf16 A): counted-vmcnt double-buffer + T2 swizzle.
// 128x128 tile, BK=64, 4 waves 2x2. Buffers A0/A1/B0/B1 each 128x64 (16KB).
// Staging: lane fetches global granule (lane&7)^(lane>>3) of its row; LDS
// linear. Read: granule g of row R at LDS granule g^(R&7), R&7 == col&7.
// --------------------------------------------------------------------------
__device__ __forceinline__ void stage8(const ushort* a_src, const ushort* b_src,
                                       ushort* as, ushort* bs, int w, int k0) {
#pragma unroll
  for (int c = 0; c < 4; ++c) {
    gld16(a_src + (size_t)c * 32 * 1024 + k0, as + (w * 8 + c * 32) * 64);
    gld16(b_src + (size_t)c * 32 * 1024 + k0, bs + (w * 8 + c * 32) * 64);
  }
}

template <bool F32OUT>
__device__ __forceinline__ void core_bb_pipe(ushort* __restrict__ S,
                                             const ushort* __restrict__ A,
                                             const ushort* __restrict__ Bt,
                                             const float* __restrict__ bias,
                                             void* __restrict__ Cv,
                                             float oscale, int bx, int by) {
  ushort* A0 = S;                  // 4 x 16KB buffers
  ushort* B0 = S + 128 * 64;
  ushort* A1 = S + 2 * 128 * 64;
  ushort* B1 = S + 3 * 128 * 64;
  const int n0 = bx * 128;
  const int m0 = by * 128;
  const int t = threadIdx.x;
  const int lane = t & 63;
  const int w = t >> 6;
  const int wm = w >> 1, wn = w & 1;
  const int col = lane & 15;
  const int quad = lane >> 4;
  const int gr = lane >> 3;                    // 0..7 (row within 8-row chunk)
  const int gc = ((lane & 7) ^ gr) * 8;        // SWIZZLED source granule
  const int s7 = col & 7;                      // read-side row parity

  f32x4 acc[4][4];
#pragma unroll
  for (int i = 0; i < 4; ++i)
#pragma unroll
    for (int j = 0; j < 4; ++j) acc[i][j] = (f32x4){0.f, 0.f, 0.f, 0.f};

  const ushort* a_src = A + (size_t)(m0 + w * 8 + gr) * 1024 + gc;
  const ushort* b_src = Bt + (size_t)(n0 + w * 8 + gr) * 1024 + gc;

  auto compute = [&](const ushort* asb, const ushort* bsb) {
#pragma unroll
    for (int half = 0; half < 2; ++half) {
      bf16x8 af[4], bfr[4];
      const int g0 = half * 4 + quad;          // logical granule of this read
      const int gs = (g0 ^ s7) << 3;           // swizzled LDS offset (ushorts)
#pragma unroll
      for (int i = 0; i < 4; ++i)
        af[i] = ld8(&asb[(wm * 64 + i * 16 + col) * 64 + gs]);
#pragma unroll
      for (int j = 0; j < 4; ++j)
        bfr[j] = ld8(&bsb[(wn * 64 + j * 16 + col) * 64 + gs]);
#pragma unroll
      for (int i = 0; i < 4; ++i)
#pragma unroll
        for (int j = 0; j < 4; ++j)
          acc[i][j] = __builtin_amdgcn_mfma_f32_16x16x32_bf16(af[i], bfr[j],
                                                              acc[i][j], 0, 0, 0);
    }
  };

  // prologue: tile 0 -> buf0 (8 loads in flight)
  stage8(a_src, b_src, A0, B0, w, 0);

  for (int t2 = 0; t2 < 16; t2 += 2) {
    // even step: read buf0, stage t2+1 -> buf1
    stage8(a_src, b_src, A1, B1, w, (t2 + 1) * 64);
    asm volatile("s_waitcnt vmcnt(8)" ::: "memory");  // prev tile landed
    __builtin_amdgcn_sched_barrier(0);
    __builtin_amdgcn_s_barrier();
    __builtin_amdgcn_sched_barrier(0);
    compute(A0, B0);
    asm volatile("s_waitcnt lgkmcnt(0)" ::: "memory");  // my reads retired
    __builtin_amdgcn_sched_barrier(0);
    __builtin_amdgcn_s_barrier();

    // odd step: read buf1, stage t2+2 -> buf0 (skip on last)
    if (t2 < 14) {
      stage8(a_src, b_src, A0, B0, w, (t2 + 2) * 64);
      asm volatile("s_waitcnt vmcnt(8)" ::: "memory");
    } else {
      asm volatile("s_waitcnt vmcnt(0)" ::: "memory");
    }
    __builtin_amdgcn_sched_barrier(0);
    __builtin_amdgcn_s_barrier();
    __builtin_amdgcn_sched_barrier(0);
    compute(A1, B1);
    asm volatile("s_waitcnt lgkmcnt(0)" ::: "memory");
    __builtin_amdgcn_sched_barrier(0);
    __builtin_amdgcn_s_barrier();
  }

#pragma unroll
  for (int i = 0; i < 4; ++i)
#pragma unroll
    for (int j = 0; j < 4; ++j) {
      const int n = n0 + wn * 64 + j * 16 + col;
      float bv = 0.f;
      if (F32OUT) bv = bias[n];
#pragma unroll
      for (int r = 0; r < 4; ++r) {
        const int m = m0 + wm * 64 + i * 16 + quad * 4 + r;
        if (F32OUT)
          reinterpret_cast<float*>(Cv)[(size_t)m * 1024 + n] = acc[i][j][r] + bv;
        else
          reinterpret_cast<ushort*>(Cv)[(size_t)m * 1024 + n] =
              f2bf(acc[i][j][r] * oscale);
      }
    }
}

// --------------------------------------------------------------------------
// GEMM core (fp32 A, in-kernel cvt): A staged via cvt16 into stride-72 LDS
// (R7-verified layout; already conflict-broken), B via gld16 + T2 swizzle.
// Single-buffer. Uses S[0..17408).
// --------------------------------------------------------------------------
__device__ __forceinline__ void core_f32a(ushort* __restrict__ S,
                                          const float* __restrict__ A,
                                          const ushort* __restrict__ Bt,
                                          ushort* __restrict__ C, int bx,
                                          int by) {
  ushort* As72 = S;                 // 128*72
  ushort* Bs = S + 128 * 72;        // 128*64
  const int n0 = bx * 128;
  const int m0 = by * 128;
  const int t = threadIdx.x;
  const int lane = t & 63;
  const int w = t >> 6;
  const int wm = w >> 1, wn = w & 1;
  const int col = lane & 15;
  const int quad = lane >> 4;
  const int gr = lane >> 3;
  const int gc = ((lane & 7) ^ gr) * 8;        // SWIZZLED source granule (B)
  const int s7 = col & 7;
  const int srow = t >> 1;        // 0..127
  const int sc0 = (t & 1) * 32;   // 0 or 32

  f32x4 acc[4][4];
#pragma unroll
  for (int i = 0; i < 4; ++i)
#pragma unroll
    for (int j = 0; j < 4; ++j) acc[i][j] = (f32x4){0.f, 0.f, 0.f, 0.f};

  const float* a_src = A + (size_t)(m0 + srow) * 1024 + sc0;
  const ushort* b_src = Bt + (size_t)(n0 + w * 8 + gr) * 1024 + gc;
  ushort* bs_base = &Bs[(w * 8) * 64];

  for (int k0 = 0; k0 < 1024; k0 += 64) {
#pragma unroll
    for (int c = 0; c < 4; ++c)
      gld16(b_src + (size_t)c * 32 * 1024 + k0, bs_base + c * 32 * 64);
    cvt16(a_src + k0, &As72[srow * 72 + sc0]);
    cvt16(a_src + k0 + 16, &As72[srow * 72 + sc0 + 16]);
    __syncthreads();

#pragma unroll
    for (int half = 0; half < 2; ++half) {
      bf16x8 af[4], bfr[4];
      const int gs = ((half * 4 + quad) ^ s7) << 3;
#pragma unroll
      for (int i = 0; i < 4; ++i)
        af[i] = ld8(&As72[(wm * 64 + i * 16 + col) * 72 + half * 32 + quad * 8]);
#pragma unroll
      for (int j = 0; j < 4; ++j)
        bfr[j] = ld8(&Bs[(wn * 64 + j * 16 + col) * 64 + gs]);
#pragma unroll
      for (int i = 0; i < 4; ++i)
#pragma unroll
        for (int j = 0; j < 4; ++j)
          acc[i][j] = __builtin_amdgcn_mfma_f32_16x16x32_bf16(af[i], bfr[j],
                                                              acc[i][j], 0, 0, 0);
    }
    __syncthreads();
  }

#pragma unroll
  for (int i = 0; i < 4; ++i)
#pragma unroll
    for (int j = 0; j < 4; ++j) {
      const int n = n0 + wn * 64 + j * 16 + col;
#pragma unroll
      for (int r = 0; r < 4; ++r) {
        const int m = m0 + wm * 64 + i * 16 + quad * 4 + r;
        C[(size_t)m * 1024 + n] = f2bf(acc[i][j][r]);
      }
    }
}

// OUT gemm: C fp32 + bias. grid 512 (1D, XCD-chunked decode).
__global__ __launch_bounds__(256) void gemm_out(const ushort* __restrict__ A,
                                                const ushort* __restrict__ Bt,
                                                const float* __restrict__ bias,
                                                float* __restrict__ C) {
  __shared__ __align__(16) ushort S[4 * 128 * 64];
  const int id = blockIdx.x;
  const int bx = (id >> 3) & 7;
  const int by = ((id >> 6) << 3) | (id & 7);
  core_bb_pipe<true>(S, A, Bt, bias, C, 1.0f, bx, by);
}

// All three projections in one launch. grid 1536 (1D, XCD-chunked decode).
// id = 64*a + 8*bx + b; by = 8*a + b (0..191). by<64: q (scale 2^-5 folded);
// <128: k; else: v (fp32 A, single-buffer path).
__global__ __launch_bounds__(256) void gemm_proj3(
    const ushort* __restrict__ Aq, const ushort* __restrict__ Bq,
    ushort* __restrict__ Cq, const ushort* __restrict__ Ak,
    const ushort* __restrict__ Bk, ushort* __restrict__ Ck,
    const float* __restrict__ Av, const ushort* __restrict__ Bv,
    ushort* __restrict__ Cvp) {
  __shared__ __align__(16) ushort S[4 * 128 * 64];  // 64KB shared pool
  const int id = blockIdx.x;
  const int bx = (id >> 3) & 7;
  const int by = ((id >> 6) << 3) | (id & 7);
  if (by < 64)
    core_bb_pipe<false>(S, Aq, Bq, nullptr, Cq, 0.03125f, bx, by);
  else if (by < 128)
    core_bb_pipe<false>(S, Ak, Bk, nullptr, Ck, 1.0f, bx, by - 64);
  else
    core_f32a(S, Av, Bv, Cvp, bx, by - 128);
}

// --------------------------------------------------------------------------
// Flash attention, 128-row q-tiles. Q,K,V,O bf16 [8192][1024], O aliases Q.
// Q PRE-SCALED by 1/sqrt(1024). grid 1024; block 256 (4 waves); wave w owns
// q-rows w*32..+31. Swapped QK^T (lane-local softmax rows). K staged via
// gld16 + granule XOR swizzle into linear Ks[64][64]. Defer-max (THR=8).
// Barriers: 2/kt. LDS 35 KB. UNCHANGED from R11 (control).
// --------------------------------------------------------------------------
__global__ __launch_bounds__(256) void flash_attn(const ushort* __restrict__ Q,
                                                  const ushort* __restrict__ K,
                                                  const ushort* __restrict__ V,
                                                  ushort* __restrict__ O) {
  __shared__ __align__(16) ushort QP[128 * 72];
  __shared__ __align__(16) ushort Ks[64 * 64];
  __shared__ __align__(16) ushort Vt[64 * 72];
  const int pair = blockIdx.x & 127;
  const int b = pair >> 4;
  const int h = pair & 15;
  const int qt = blockIdx.x >> 7;
  const int t = threadIdx.x;
  const int lane = t & 63;
  const int w = t >> 6;
  const int col = lane & 15;
  const int quad = lane >> 4;

  const size_t base = (size_t)b * 1024 * 1024 + h * 64;
  const int qrow0 = qt * 128;

  // stage Q (128 x 64): 32 ushorts per thread
  {
    const int row = t >> 1;
    const int c0 = (t & 1) * 32;
    const ushort* src = Q + base + (size_t)(qrow0 + row) * 1024 + c0;
    uint4 v0 = reinterpret_cast<const uint4*>(src)[0];
    uint4 v1 = reinterpret_cast<const uint4*>(src)[1];
    uint4 v2 = reinterpret_cast<const uint4*>(src)[2];
    uint4 v3 = reinterpret_cast<const uint4*>(src)[3];
    reinterpret_cast<uint4*>(&QP[row * 72 + c0])[0] = v0;
    reinterpret_cast<uint4*>(&QP[row * 72 + c0])[1] = v1;
    reinterpret_cast<uint4*>(&QP[row * 72 + c0])[2] = v2;
    reinterpret_cast<uint4*>(&QP[row * 72 + c0])[3] = v3;
  }
  __syncthreads();
  bf16x8 qa[2][2];
#pragma unroll
  for (int g = 0; g < 2; ++g)
#pragma unroll
    for (int half = 0; half < 2; ++half)
      qa[g][half] =
          ld8(&QP[(w * 32 + g * 16 + col) * 72 + half * 32 + quad * 8]);
  // qa reads complete before the first kt staging barrier -> reusing QP as
  // the P buffer afterwards is race-free.

  f32x4 o_[2][4];
#pragma unroll
  for (int g = 0; g < 2; ++g)
#pragma unroll
    for (int c = 0; c < 4; ++c) o_[g][c] = (f32x4){0.f, 0.f, 0.f, 0.f};
  float m_s[2] = {-1e30f, -1e30f};
  float l_s[2] = {0.f, 0.f};

  // K staging geometry (swizzled gld16): wave w covers rows w*16..w*16+15
  const int krow = w * 16 + (lane >> 3);
  const int kcs = (((lane & 7) ^ (lane >> 3)) << 3);  // swizzled ushort col
  const int s7 = col & 7;

  for (int kt = 0; kt < 16; ++kt) {
    // stage K via DMA (swizzled source) and V transposed (reg path)
    {
      const ushort* k0 = K + base + (size_t)(kt * 64 + krow) * 1024 + kcs;
      gld16(k0, &Ks[(w * 16) * 64]);
      gld16(k0 + 8 * 1024, &Ks[(w * 16 + 8) * 64]);
      const int vs = t & 63;
      const int ve = (t >> 6) * 16;
      const ushort* vsrc = V + base + (size_t)(kt * 64 + vs) * 1024 + ve;
      union { uint4 u[2]; ushort s[16]; } vv;
      vv.u[0] = reinterpret_cast<const uint4*>(vsrc)[0];
      vv.u[1] = reinterpret_cast<const uint4*>(vsrc)[1];
#pragma unroll
      for (int j = 0; j < 16; ++j) Vt[(ve + j) * 72 + vs] = vv.s[j];
    }
    __syncthreads();

    // S^T = K Q^T; sc[g][c][r] = S[q=lane&15(+g*16+w*32)][k=c*16+quad*4+r]
    f32x4 sc[2][4];
#pragma unroll
    for (int c = 0; c < 4; ++c) {
      const int R = (c * 16 + col) * 64;
      bf16x8 kb0 = ld8(&Ks[R + ((quad ^ s7) << 3)]);
      bf16x8 kb1 = ld8(&Ks[R + (((quad + 4) ^ s7) << 3)]);
#pragma unroll
      for (int g = 0; g < 2; ++g) {
        f32x4 z = {0.f, 0.f, 0.f, 0.f};
        z = __builtin_amdgcn_mfma_f32_16x16x32_bf16(kb0, qa[g][0], z, 0, 0, 0);
        z = __builtin_amdgcn_mfma_f32_16x16x32_bf16(kb1, qa[g][1], z, 0, 0, 0);
        sc[g][c] = z;
      }
    }

    // online softmax, row-local, with defer-max (THR=8)
    float al[2];
    bool df[2];
#pragma unroll
    for (int g = 0; g < 2; ++g) {
      float mx = sc[g][0][0];
#pragma unroll
      for (int c = 0; c < 4; ++c)
#pragma unroll
        for (int r = 0; r < 4; ++r) mx = fmaxf(mx, sc[g][c][r]);
      mx = fmaxf(mx, __shfl_xor(mx, 16));
      mx = fmaxf(mx, __shfl_xor(mx, 32));
      df[g] = __all(mx - m_s[g] <= 8.0f) != 0;
      if (df[g]) {
        al[g] = 1.0f;
      } else {
        const float m_new = fmaxf(m_s[g], mx);
        al[g] = __expf(m_s[g] - m_new);
        m_s[g] = m_new;
      }
      float rs = 0.f;
      const int prow = (w * 32 + g * 16 + col) * 72;
#pragma unroll
      for (int c = 0; c < 4; ++c) {
        const float p0 = __expf(sc[g][c][0] - m_s[g]);
        const float p1 = __expf(sc[g][c][1] - m_s[g]);
        const float p2 = __expf(sc[g][c][2] - m_s[g]);
        const float p3 = __expf(sc[g][c][3] - m_s[g]);
        rs += (p0 + p1) + (p2 + p3);
        union { uint2 u; ushort s[4]; } pk;
        pk.s[0] = f2bf(p0);
        pk.s[1] = f2bf(p1);
        pk.s[2] = f2bf(p2);
        pk.s[3] = f2bf(p3);
        *reinterpret_cast<uint2*>(&QP[prow + c * 16 + quad * 4]) = pk.u;
      }
      rs += __shfl_xor(rs, 16);
      rs += __shfl_xor(rs, 32);
      l_s[g] = df[g] ? (l_s[g] + rs) : (l_s[g] * al[g] + rs);
    }

    // rescale O with per-row alpha (skipped entirely when deferred)
#pragma unroll
    for (int g = 0; g < 2; ++g)
      if (!df[g]) {
#pragma unroll
        for (int r = 0; r < 4; ++r) {
          const float a = __shfl(al[g], (lane & 48) | (quad * 4 + r));
          o_[g][0][r] *= a;
          o_[g][1][r] *= a;
          o_[g][2][r] *= a;
          o_[g][3][r] *= a;
        }
      }

    // O += P V (own-wave P rows; no barrier needed before reads)
    bf16x8 pa[2][2];
#pragma unroll
    for (int g = 0; g < 2; ++g)
#pragma unroll
      for (int half = 0; half < 2; ++half)
        pa[g][half] =
            ld8(&QP[(w * 32 + g * 16 + col) * 72 + half * 32 + quad * 8]);
#pragma unroll
    for (int c = 0; c < 4; ++c) {
      bf16x8 vb0 = ld8(&Vt[(c * 16 + col) * 72 + quad * 8]);
      bf16x8 vb1 = ld8(&Vt[(c * 16 + col) * 72 + 32 + quad * 8]);
#pragma unroll
      for (int g = 0; g < 2; ++g) {
        o_[g][c] = __builtin_amdgcn_mfma_f32_16x16x32_bf16(pa[g][0], vb0,
                                                           o_[g][c], 0, 0, 0);
        o_[g][c] = __builtin_amdgcn_mfma_f32_16x16x32_bf16(pa[g][1], vb1,
                                                           o_[g][c], 0, 0, 0);
      }
    }
    __syncthreads();
  }

#pragma unroll
  for (int g = 0; g < 2; ++g)
#pragma unroll
    for (int r = 0; r < 4; ++r) {
      const float lr = __shfl(l_s[g], (lane & 48) | (quad * 4 + r));
      const float inv = 1.f / lr;
      const size_t row =
          base + (size_t)(qrow0 + w * 32 + g * 16 + quad * 4 + r) * 1024;
      O[row + 0 + col] = f2bf(o_[g][0][r] * inv);
      O[row + 16 + col] = f2bf(o_[g][1][r] * inv);
      O[row + 32 + col] = f2bf(o_[g][2][r] * inv);
      O[row + 48 + col] = f2bf(o_[g][3][r] * inv);
    }
}

// --------------------------------------------------------------------------
extern "C" void kernel_launch(void* const* d_in, const int* in_sizes, int n_in,
                              void* d_out, int out_size, void* d_ws, size_t ws_size,
                              hipStream_t stream) {
  const float* q = (const float*)d_in[0];
  const float* k = (const float*)d_in[1];
  const float* v = (const float*)d_in[2];
  const float* Wq = (const float*)d_in[3];
  const float* Wk = (const float*)d_in[4];
  const float* Wv = (const float*)d_in[5];
  const float* Wo = (const float*)d_in[6];
  const float* bo = (const float*)d_in[7];
  float* out = (float*)d_out;
  ushort* ws = (ushort*)d_ws;

  const size_t M8 = 8u << 20;  // 8M bf16 = 16 MB
  const size_t M1 = 1u << 20;
  ushort* Qp = ws;                 // also flash output (in-place)
  ushort* Kp = ws + M8;
  ushort* Vp = ws + 2 * M8;
  ushort* WqT = ws + 3 * M8;
  ushort* WkT = WqT + M1;
  ushort* WvT = WkT + M1;
  ushort* WoB = WvT + M1;          // total 56 MB

  // d_out (32 MB fp32) as bf16 scratch: q~ at 0, k~ at +16MB.
  ushort* X0 = (ushort*)d_out;
  ushort* X1 = X0 + M8;

  prep_wt3<<<768, 256, 0, stream>>>(Wq, Wk, Wv, WqT, WkT, WvT);
  cvt3<<<4352, 256, 0, stream>>>(q, X0, k, X1, Wo, WoB);
  // attn scale folded into Q projection (exact: 2^-5 exponent shift in bf16)
  gemm_proj3<<<1536, 256, 0, stream>>>(X0, WqT, Qp, X1, WkT, Kp, v, WvT, Vp);

  flash_attn<<<1024, 256, 0, stream>>>(Qp, Kp, Vp, Qp);

  gemm_out<<<512, 256, 0, stream>>>(Qp, WoB, bo, out);
}

// Round 8
// 320.575 us; speedup vs baseline: 1.1991x; 1.0239x over previous
//
#include <hip/hip_runtime.h>
#include <stdint.h>

// ---------------------------------------------------------------------------
// MultiHeadAttention: B=8 S=1024 QKV=1024 H=16 E=64 OUT=1024.
// fp32 in / fp32 out, bf16 MFMA internals, fp32 accum.
// R15: VALU cut via native bf16 casts + T5 setprio in flash.
//  - f2bf: manual RNE bit-twiddle -> native __bf16 cast. Compiler emits
//    v_cvt_pk_bf16_f32 (RNE, 2 vals/inst) instead of ~4 VALU/val (m240:
//    compiler cast is the fast path). Hits flash P-pack (32 vals/kt/thr),
//    cvt3/prep_wt3 bulk cvt, gemm epilogues.
//  - flash: __builtin_amdgcn_s_setprio(1/0) around QK^T + PV MFMA clusters
//    (T5; m191 regime: 3-4 blocks/CU at different kt phases).
// R14 kept: T2 granule-XOR swizzle (conflicts 16.78M->1.05M verified).
// R13 kept: counted-vmcnt dbuf pipe. R12 kept: XCD-chunked 1D decode.
// flash MFMA maps (HW-verified m89/m91):
//   A[m=lane&15][k=quad*8+j], B[k=quad*8+j][n=lane&15], D[row=quad*4+r][col]
// ws: [Qp 16][Kp 16][Vp 16][WqT 2|WkT 2|WvT 2|WoB 2] = 56 MB.
// d_out doubles as bf16 scratch (q~ at 0, k~ at 16MB).
// ---------------------------------------------------------------------------

typedef __bf16 bf16x8 __attribute__((ext_vector_type(8)));
typedef float f32x4 __attribute__((ext_vector_type(4)));

typedef __attribute__((address_space(3))) uint32_t lds_u32;
typedef const __attribute__((address_space(1))) uint32_t glb_u32;

// Native cast -> compiler emits v_cvt_pk_bf16_f32 (RNE), packing pairs.
__device__ __forceinline__ ushort f2bf(float f) {
  union { __bf16 b; ushort u; } c;
  c.b = (__bf16)f;
  return c.u;
}
__device__ __forceinline__ bf16x8 ld8(const ushort* p) {
  union { uint4 u; bf16x8 b; } c;
  c.u = *reinterpret_cast<const uint4*>(p);
  return c.b;
}
__device__ __forceinline__ void cvt16(const float* __restrict__ src,
                                      ushort* __restrict__ dst) {
  union { uint4 u[2]; ushort s[16]; } o;
#pragma unroll
  for (int i = 0; i < 4; ++i) {
    const float4 f = reinterpret_cast<const float4*>(src)[i];
    o.s[4 * i + 0] = f2bf(f.x);
    o.s[4 * i + 1] = f2bf(f.y);
    o.s[4 * i + 2] = f2bf(f.z);
    o.s[4 * i + 3] = f2bf(f.w);
  }
  reinterpret_cast<uint4*>(dst)[0] = o.u[0];
  reinterpret_cast<uint4*>(dst)[1] = o.u[1];
}

// global->LDS DMA, 16B/lane. LDS dest wave-uniform base + lane*16 (m104/m108).
__device__ __forceinline__ void gld16(const ushort* g, ushort* l) {
  __builtin_amdgcn_global_load_lds((glb_u32*)g, (lds_u32*)l, 16, 0, 0);
}

// --------------------------------------------------------------------------
// W[16][1024][64] fp32 -> WT[1024][1024] bf16 (WT[n=h*64+e][k]).
// 3 weights in one launch: grid 768 (bid>>8 selects W). 256 thr.
// --------------------------------------------------------------------------
__global__ __launch_bounds__(256) void prep_wt3(
    const float* __restrict__ W0, const float* __restrict__ W1,
    const float* __restrict__ W2, ushort* __restrict__ T0,
    ushort* __restrict__ T1, ushort* __restrict__ T2) {
  __shared__ __align__(16) ushort tile[64 * 72];
  const int sel = blockIdx.x >> 8;
  const float* W = sel == 0 ? W0 : sel == 1 ? W1 : W2;
  ushort* WT = sel == 0 ? T0 : sel == 1 ? T1 : T2;
  const int bid = blockIdx.x & 255;
  const int h = bid >> 4;
  const int kt = bid & 15;
  const int t = threadIdx.x;
  const int row = t >> 2;
  const int ch = (t & 3) * 16;
  cvt16(W + ((size_t)h * 1024 + kt * 64 + row) * 64 + ch, &tile[row * 72 + ch]);
  __syncthreads();
  const int e = t >> 2;
  const int kc = (t & 3) * 16;
  ushort vals[16];
#pragma unroll
  for (int j = 0; j < 16; ++j) vals[j] = tile[(kc + j) * 72 + e];
  ushort* dst = WT + (size_t)(h * 64 + e) * 1024 + kt * 64 + kc;
  reinterpret_cast<uint4*>(dst)[0] = *reinterpret_cast<uint4*>(&vals[0]);
  reinterpret_cast<uint4*>(dst)[1] = *reinterpret_cast<uint4*>(&vals[8]);
}

// q (8M) + k (8M) + Wo (1M) fp32->bf16 in one launch. grid 4352.
__global__ __launch_bounds__(256) void cvt3(const float* __restrict__ s0,
                                            ushort* __restrict__ d0,
                                            const float* __restrict__ s1,
                                            ushort* __restrict__ d1,
                                            const float* __restrict__ s2,
                                            ushort* __restrict__ d2) {
  int b = blockIdx.x;
  const float* s;
  ushort* d;
  if (b < 2048) { s = s0; d = d0; }
  else if (b < 4096) { s = s1; d = d1; b -= 2048; }
  else { s = s2; d = d2; b -= 4096; }
  const int i = (b * 256 + threadIdx.x) * 16;
  cvt16(s + i, d + i);
}

// --------------------------------------------------------------------------
// Pipelined GEMM core (bf16 A): counted-vmcnt double-buffer + T2 swizzle.
// 128x128 tile, BK=64, 4 waves 2x2. Buffers A0/A1/B0/B1 each 128x64 (16KB).
// Staging: lane fetches global granule (lane&7)^(lane>>3) of its row; LDS
// linear. Read: granule g of row R at LDS granule g^(R&7), R&7 == col&7.
// --------------------------------------------------------------------------
__device__ __forceinline__ void stage8(const ushort* a_src, const ushort* b_src,
                                       ushort* as, ushort* bs, int w, int k0) {
#pragma unroll
  for (int c = 0; c < 4; ++c) {
    gld16(a_src + (size_t)c * 32 * 1024 + k0, as + (w * 8 + c * 32) * 64);
    gld16(b_src + (size_t)c * 32 * 1024 + k0, bs + (w * 8 + c * 32) * 64);
  }
}

template <bool F32OUT>
__device__ __forceinline__ void core_bb_pipe(ushort* __restrict__ S,
                                             const ushort* __restrict__ A,
                                             const ushort* __restrict__ Bt,
                                             const float* __restrict__ bias,
                                             void* __restrict__ Cv,
                                             float oscale, int bx, int by) {
  ushort* A0 = S;                  // 4 x 16KB buffers
  ushort* B0 = S + 128 * 64;
  ushort* A1 = S + 2 * 128 * 64;
  ushort* B1 = S + 3 * 128 * 64;
  const int n0 = bx * 128;
  const int m0 = by * 128;
  const int t = threadIdx.x;
  const int lane = t & 63;
  const int w = t >> 6;
  const int wm = w >> 1, wn = w & 1;
  const int col = lane & 15;
  const int quad = lane >> 4;
  const int gr = lane >> 3;                    // 0..7 (row within 8-row chunk)
  const int gc = ((lane & 7) ^ gr) * 8;        // SWIZZLED source granule
  const int s7 = col & 7;                      // read-side row parity

  f32x4 acc[4][4];
#pragma unroll
  for (int i = 0; i < 4; ++i)
#pragma unroll
    for (int j = 0; j < 4; ++j) acc[i][j] = (f32x4){0.f, 0.f, 0.f, 0.f};

  const ushort* a_src = A + (size_t)(m0 + w * 8 + gr) * 1024 + gc;
  const ushort* b_src = Bt + (size_t)(n0 + w * 8 + gr) * 1024 + gc;

  auto compute = [&](const ushort* asb, const ushort* bsb) {
#pragma unroll
    for (int half = 0; half < 2; ++half) {
      bf16x8 af[4], bfr[4];
      const int g0 = half * 4 + quad;          // logical granule of this read
      const int gs = (g0 ^ s7) << 3;           // swizzled LDS offset (ushorts)
#pragma unroll
      for (int i = 0; i < 4; ++i)
        af[i] = ld8(&asb[(wm * 64 + i * 16 + col) * 64 + gs]);
#pragma unroll
      for (int j = 0; j < 4; ++j)
        bfr[j] = ld8(&bsb[(wn * 64 + j * 16 + col) * 64 + gs]);
#pragma unroll
      for (int i = 0; i < 4; ++i)
#pragma unroll
        for (int j = 0; j < 4; ++j)
          acc[i][j] = __builtin_amdgcn_mfma_f32_16x16x32_bf16(af[i], bfr[j],
                                                              acc[i][j], 0, 0, 0);
    }
  };

  // prologue: tile 0 -> buf0 (8 loads in flight)
  stage8(a_src, b_src, A0, B0, w, 0);

  for (int t2 = 0; t2 < 16; t2 += 2) {
    // even step: read buf0, stage t2+1 -> buf1
    stage8(a_src, b_src, A1, B1, w, (t2 + 1) * 64);
    asm volatile("s_waitcnt vmcnt(8)" ::: "memory");  // prev tile landed
    __builtin_amdgcn_sched_barrier(0);
    __builtin_amdgcn_s_barrier();
    __builtin_amdgcn_sched_barrier(0);
    compute(A0, B0);
    asm volatile("s_waitcnt lgkmcnt(0)" ::: "memory");  // my reads retired
    __builtin_amdgcn_sched_barrier(0);
    __builtin_amdgcn_s_barrier();

    // odd step: read buf1, stage t2+2 -> buf0 (skip on last)
    if (t2 < 14) {
      stage8(a_src, b_src, A0, B0, w, (t2 + 2) * 64);
      asm volatile("s_waitcnt vmcnt(8)" ::: "memory");
    } else {
      asm volatile("s_waitcnt vmcnt(0)" ::: "memory");
    }
    __builtin_amdgcn_sched_barrier(0);
    __builtin_amdgcn_s_barrier();
    __builtin_amdgcn_sched_barrier(0);
    compute(A1, B1);
    asm volatile("s_waitcnt lgkmcnt(0)" ::: "memory");
    __builtin_amdgcn_sched_barrier(0);
    __builtin_amdgcn_s_barrier();
  }

#pragma unroll
  for (int i = 0; i < 4; ++i)
#pragma unroll
    for (int j = 0; j < 4; ++j) {
      const int n = n0 + wn * 64 + j * 16 + col;
      float bv = 0.f;
      if (F32OUT) bv = bias[n];
#pragma unroll
      for (int r = 0; r < 4; ++r) {
        const int m = m0 + wm * 64 + i * 16 + quad * 4 + r;
        if (F32OUT)
          reinterpret_cast<float*>(Cv)[(size_t)m * 1024 + n] = acc[i][j][r] + bv;
        else
          reinterpret_cast<ushort*>(Cv)[(size_t)m * 1024 + n] =
              f2bf(acc[i][j][r] * oscale);
      }
    }
}

// --------------------------------------------------------------------------
// GEMM core (fp32 A, in-kernel cvt): A staged via cvt16 into stride-72 LDS
// (R7-verified layout; already conflict-broken), B via gld16 + T2 swizzle.
// Single-buffer. Uses S[0..17408).
// --------------------------------------------------------------------------
__device__ __forceinline__ void core_f32a(ushort* __restrict__ S,
                                          const float* __restrict__ A,
                                          const ushort* __restrict__ Bt,
                                          ushort* __restrict__ C, int bx,
                                          int by) {
  ushort* As72 = S;                 // 128*72
  ushort* Bs = S + 128 * 72;        // 128*64
  const int n0 = bx * 128;
  const int m0 = by * 128;
  const int t = threadIdx.x;
  const int lane = t & 63;
  const int w = t >> 6;
  const int wm = w >> 1, wn = w & 1;
  const int col = lane & 15;
  const int quad = lane >> 4;
  const int gr = lane >> 3;
  const int gc = ((lane & 7) ^ gr) * 8;        // SWIZZLED source granule (B)
  const int s7 = col & 7;
  const int srow = t >> 1;        // 0..127
  const int sc0 = (t & 1) * 32;   // 0 or 32

  f32x4 acc[4][4];
#pragma unroll
  for (int i = 0; i < 4; ++i)
#pragma unroll
    for (int j = 0; j < 4; ++j) acc[i][j] = (f32x4){0.f, 0.f, 0.f, 0.f};

  const float* a_src = A + (size_t)(m0 + srow) * 1024 + sc0;
  const ushort* b_src = Bt + (size_t)(n0 + w * 8 + gr) * 1024 + gc;
  ushort* bs_base = &Bs[(w * 8) * 64];

  for (int k0 = 0; k0 < 1024; k0 += 64) {
#pragma unroll
    for (int c = 0; c < 4; ++c)
      gld16(b_src + (size_t)c * 32 * 1024 + k0, bs_base + c * 32 * 64);
    cvt16(a_src + k0, &As72[srow * 72 + sc0]);
    cvt16(a_src + k0 + 16, &As72[srow * 72 + sc0 + 16]);
    __syncthreads();

#pragma unroll
    for (int half = 0; half < 2; ++half) {
      bf16x8 af[4], bfr[4];
      const int gs = ((half * 4 + quad) ^ s7) << 3;
#pragma unroll
      for (int i = 0; i < 4; ++i)
        af[i] = ld8(&As72[(wm * 64 + i * 16 + col) * 72 + half * 32 + quad * 8]);
#pragma unroll
      for (int j = 0; j < 4; ++j)
        bfr[j] = ld8(&Bs[(wn * 64 + j * 16 + col) * 64 + gs]);
#pragma unroll
      for (int i = 0; i < 4; ++i)
#pragma unroll
        for (int j = 0; j < 4; ++j)
          acc[i][j] = __builtin_amdgcn_mfma_f32_16x16x32_bf16(af[i], bfr[j],
                                                              acc[i][j], 0, 0, 0);
    }
    __syncthreads();
  }

#pragma unroll
  for (int i = 0; i < 4; ++i)
#pragma unroll
    for (int j = 0; j < 4; ++j) {
      const int n = n0 + wn * 64 + j * 16 + col;
#pragma unroll
      for (int r = 0; r < 4; ++r) {
        const int m = m0 + wm * 64 + i * 16 + quad * 4 + r;
        C[(size_t)m * 1024 + n] = f2bf(acc[i][j][r]);
      }
    }
}

// OUT gemm: C fp32 + bias. grid 512 (1D, XCD-chunked decode).
__global__ __launch_bounds__(256) void gemm_out(const ushort* __restrict__ A,
                                                const ushort* __restrict__ Bt,
                                                const float* __restrict__ bias,
                                                float* __restrict__ C) {
  __shared__ __align__(16) ushort S[4 * 128 * 64];
  const int id = blockIdx.x;
  const int bx = (id >> 3) & 7;
  const int by = ((id >> 6) << 3) | (id & 7);
  core_bb_pipe<true>(S, A, Bt, bias, C, 1.0f, bx, by);
}

// All three projections in one launch. grid 1536 (1D, XCD-chunked decode).
// id = 64*a + 8*bx + b; by = 8*a + b (0..191). by<64: q (scale 2^-5 folded);
// <128: k; else: v (fp32 A, single-buffer path).
__global__ __launch_bounds__(256) void gemm_proj3(
    const ushort* __restrict__ Aq, const ushort* __restrict__ Bq,
    ushort* __restrict__ Cq, const ushort* __restrict__ Ak,
    const ushort* __restrict__ Bk, ushort* __restrict__ Ck,
    const float* __restrict__ Av, const ushort* __restrict__ Bv,
    ushort* __restrict__ Cvp) {
  __shared__ __align__(16) ushort S[4 * 128 * 64];  // 64KB shared pool
  const int id = blockIdx.x;
  const int bx = (id >> 3) & 7;
  const int by = ((id >> 6) << 3) | (id & 7);
  if (by < 64)
    core_bb_pipe<false>(S, Aq, Bq, nullptr, Cq, 0.03125f, bx, by);
  else if (by < 128)
    core_bb_pipe<false>(S, Ak, Bk, nullptr, Ck, 1.0f, bx, by - 64);
  else
    core_f32a(S, Av, Bv, Cvp, bx, by - 128);
}

// --------------------------------------------------------------------------
// Flash attention, 128-row q-tiles. Q,K,V,O bf16 [8192][1024], O aliases Q.
// Q PRE-SCALED by 1/sqrt(1024). grid 1024; block 256 (4 waves); wave w owns
// q-rows w*32..+31. Swapped QK^T (lane-local softmax rows). K staged via
// gld16 + granule XOR swizzle into linear Ks[64][64]. Defer-max (THR=8).
// R15: setprio(1/0) around MFMA clusters (T5); P-pack via native casts.
// Barriers: 2/kt. LDS 35 KB.
// --------------------------------------------------------------------------
__global__ __launch_bounds__(256) void flash_attn(const ushort* __restrict__ Q,
                                                  const ushort* __restrict__ K,
                                                  const ushort* __restrict__ V,
                                                  ushort* __restrict__ O) {
  __shared__ __align__(16) ushort QP[128 * 72];
  __shared__ __align__(16) ushort Ks[64 * 64];
  __shared__ __align__(16) ushort Vt[64 * 72];
  const int pair = blockIdx.x & 127;
  const int b = pair >> 4;
  const int h = pair & 15;
  const int qt = blockIdx.x >> 7;
  const int t = threadIdx.x;
  const int lane = t & 63;
  const int w = t >> 6;
  const int col = lane & 15;
  const int quad = lane >> 4;

  const size_t base = (size_t)b * 1024 * 1024 + h * 64;
  const int qrow0 = qt * 128;

  // stage Q (128 x 64): 32 ushorts per thread
  {
    const int row = t >> 1;
    const int c0 = (t & 1) * 32;
    const ushort* src = Q + base + (size_t)(qrow0 + row) * 1024 + c0;
    uint4 v0 = reinterpret_cast<const uint4*>(src)[0];
    uint4 v1 = reinterpret_cast<const uint4*>(src)[1];
    uint4 v2 = reinterpret_cast<const uint4*>(src)[2];
    uint4 v3 = reinterpret_cast<const uint4*>(src)[3];
    reinterpret_cast<uint4*>(&QP[row * 72 + c0])[0] = v0;
    reinterpret_cast<uint4*>(&QP[row * 72 + c0])[1] = v1;
    reinterpret_cast<uint4*>(&QP[row * 72 + c0])[2] = v2;
    reinterpret_cast<uint4*>(&QP[row * 72 + c0])[3] = v3;
  }
  __syncthreads();
  bf16x8 qa[2][2];
#pragma unroll
  for (int g = 0; g < 2; ++g)
#pragma unroll
    for (int half = 0; half < 2; ++half)
      qa[g][half] =
          ld8(&QP[(w * 32 + g * 16 + col) * 72 + half * 32 + quad * 8]);
  // qa reads complete before the first kt staging barrier -> reusing QP as
  // the P buffer afterwards is race-free.

  f32x4 o_[2][4];
#pragma unroll
  for (int g = 0; g < 2; ++g)
#pragma unroll
    for (int c = 0; c < 4; ++c) o_[g][c] = (f32x4){0.f, 0.f, 0.f, 0.f};
  float m_s[2] = {-1e30f, -1e30f};
  float l_s[2] = {0.f, 0.f};

  // K staging geometry (swizzled gld16): wave w covers rows w*16..w*16+15
  const int krow = w * 16 + (lane >> 3);
  const int kcs = (((lane & 7) ^ (lane >> 3)) << 3);  // swizzled ushort col
  const int s7 = col & 7;

  for (int kt = 0; kt < 16; ++kt) {
    // stage K via DMA (swizzled source) and V transposed (reg path)
    {
      const ushort* k0 = K + base + (size_t)(kt * 64 + krow) * 1024 + kcs;
      gld16(k0, &Ks[(w * 16) * 64]);
      gld16(k0 + 8 * 1024, &Ks[(w * 16 + 8) * 64]);
      const int vs = t & 63;
      const int ve = (t >> 6) * 16;
      const ushort* vsrc = V + base + (size_t)(kt * 64 + vs) * 1024 + ve;
      union { uint4 u[2]; ushort s[16]; } vv;
      vv.u[0] = reinterpret_cast<const uint4*>(vsrc)[0];
      vv.u[1] = reinterpret_cast<const uint4*>(vsrc)[1];
#pragma unroll
      for (int j = 0; j < 16; ++j) Vt[(ve + j) * 72 + vs] = vv.s[j];
    }
    __syncthreads();

    // S^T = K Q^T; sc[g][c][r] = S[q=lane&15(+g*16+w*32)][k=c*16+quad*4+r]
    f32x4 sc[2][4];
    __builtin_amdgcn_s_setprio(1);
#pragma unroll
    for (int c = 0; c < 4; ++c) {
      const int R = (c * 16 + col) * 64;
      bf16x8 kb0 = ld8(&Ks[R + ((quad ^ s7) << 3)]);
      bf16x8 kb1 = ld8(&Ks[R + (((quad + 4) ^ s7) << 3)]);
#pragma unroll
      for (int g = 0; g < 2; ++g) {
        f32x4 z = {0.f, 0.f, 0.f, 0.f};
        z = __builtin_amdgcn_mfma_f32_16x16x32_bf16(kb0, qa[g][0], z, 0, 0, 0);
        z = __builtin_amdgcn_mfma_f32_16x16x32_bf16(kb1, qa[g][1], z, 0, 0, 0);
        sc[g][c] = z;
      }
    }
    __builtin_amdgcn_s_setprio(0);

    // online softmax, row-local, with defer-max (THR=8)
    float al[2];
    bool df[2];
#pragma unroll
    for (int g = 0; g < 2; ++g) {
      float mx = sc[g][0][0];
#pragma unroll
      for (int c = 0; c < 4; ++c)
#pragma unroll
        for (int r = 0; r < 4; ++r) mx = fmaxf(mx, sc[g][c][r]);
      mx = fmaxf(mx, __shfl_xor(mx, 16));
      mx = fmaxf(mx, __shfl_xor(mx, 32));
      df[g] = __all(mx - m_s[g] <= 8.0f) != 0;
      if (df[g]) {
        al[g] = 1.0f;
      } else {
        const float m_new = fmaxf(m_s[g], mx);
        al[g] = __expf(m_s[g] - m_new);
        m_s[g] = m_new;
      }
      float rs = 0.f;
      const int prow = (w * 32 + g * 16 + col) * 72;
#pragma unroll
      for (int c = 0; c < 4; ++c) {
        const float p0 = __expf(sc[g][c][0] - m_s[g]);
        const float p1 = __expf(sc[g][c][1] - m_s[g]);
        const float p2 = __expf(sc[g][c][2] - m_s[g]);
        const float p3 = __expf(sc[g][c][3] - m_s[g]);
        rs += (p0 + p1) + (p2 + p3);
        union { uint2 u; ushort s[4]; } pk;
        pk.s[0] = f2bf(p0);
        pk.s[1] = f2bf(p1);
        pk.s[2] = f2bf(p2);
        pk.s[3] = f2bf(p3);
        *reinterpret_cast<uint2*>(&QP[prow + c * 16 + quad * 4]) = pk.u;
      }
      rs += __shfl_xor(rs, 16);
      rs += __shfl_xor(rs, 32);
      l_s[g] = df[g] ? (l_s[g] + rs) : (l_s[g] * al[g] + rs);
    }

    // rescale O with per-row alpha (skipped entirely when deferred)
#pragma unroll
    for (int g = 0; g < 2; ++g)
      if (!df[g]) {
#pragma unroll
        for (int r = 0; r < 4; ++r) {
          const float a = __shfl(al[g], (lane & 48) | (quad * 4 + r));
          o_[g][0][r] *= a;
          o_[g][1][r] *= a;
          o_[g][2][r] *= a;
          o_[g][3][r] *= a;
        }
      }

    // O += P V (own-wave P rows; no barrier needed before reads)
    bf16x8 pa[2][2];
#pragma unroll
    for (int g = 0; g < 2; ++g)
#pragma unroll
      for (int half = 0; half < 2; ++half)
        pa[g][half] =
            ld8(&QP[(w * 32 + g * 16 + col) * 72 + half * 32 + quad * 8]);
    __builtin_amdgcn_s_setprio(1);
#pragma unroll
    for (int c = 0; c < 4; ++c) {
      bf16x8 vb0 = ld8(&Vt[(c * 16 + col) * 72 + quad * 8]);
      bf16x8 vb1 = ld8(&Vt[(c * 16 + col) * 72 + 32 + quad * 8]);
#pragma unroll
      for (int g = 0; g < 2; ++g) {
        o_[g][c] = __builtin_amdgcn_mfma_f32_16x16x32_bf16(pa[g][0], vb0,
                                                           o_[g][c], 0, 0, 0);
        o_[g][c] = __builtin_amdgcn_mfma_f32_16x16x32_bf16(pa[g][1], vb1,
                                                           o_[g][c], 0, 0, 0);
      }
    }
    __builtin_amdgcn_s_setprio(0);
    __syncthreads();
  }

#pragma unroll
  for (int g = 0; g < 2; ++g)
#pragma unroll
    for (int r = 0; r < 4; ++r) {
      const float lr = __shfl(l_s[g], (lane & 48) | (quad * 4 + r));
      const float inv = 1.f / lr;
      const size_t row =
          base + (size_t)(qrow0 + w * 32 + g * 16 + quad * 4 + r) * 1024;
      O[row + 0 + col] = f2bf(o_[g][0][r] * inv);
      O[row + 16 + col] = f2bf(o_[g][1][r] * inv);
      O[row + 32 + col] = f2bf(o_[g][2][r] * inv);
      O[row + 48 + col] = f2bf(o_[g][3][r] * inv);
    }
}

// --------------------------------------------------------------------------
extern "C" void kernel_launch(void* const* d_in, const int* in_sizes, int n_in,
                              void* d_out, int out_size, void* d_ws, size_t ws_size,
                              hipStream_t stream) {
  const float* q = (const float*)d_in[0];
  const float* k = (const float*)d_in[1];
  const float* v = (const float*)d_in[2];
  const float* Wq = (const float*)d_in[3];
  const float* Wk = (const float*)d_in[4];
  const float* Wv = (const float*)d_in[5];
  const float* Wo = (const float*)d_in[6];
  const float* bo = (const float*)d_in[7];
  float* out = (float*)d_out;
  ushort* ws = (ushort*)d_ws;

  const size_t M8 = 8u << 20;  // 8M bf16 = 16 MB
  const size_t M1 = 1u << 20;
  ushort* Qp = ws;                 // also flash output (in-place)
  ushort* Kp = ws + M8;
  ushort* Vp = ws + 2 * M8;
  ushort* WqT = ws + 3 * M8;
  ushort* WkT = WqT + M1;
  ushort* WvT = WkT + M1;
  ushort* WoB = WvT + M1;          // total 56 MB

  // d_out (32 MB fp32) as bf16 scratch: q~ at 0, k~ at +16MB.
  ushort* X0 = (ushort*)d_out;
  ushort* X1 = X0 + M8;

  prep_wt3<<<768, 256, 0, stream>>>(Wq, Wk, Wv, WqT, WkT, WvT);
  cvt3<<<4352, 256, 0, stream>>>(q, X0, k, X1, Wo, WoB);
  // attn scale folded into Q projection (exact: 2^-5 exponent shift in bf16)
  gemm_proj3<<<1536, 256, 0, stream>>>(X0, WqT, Qp, X1, WkT, Kp, v, WvT, Vp);

  flash_attn<<<1024, 256, 0, stream>>>(Qp, Kp, Vp, Qp);

  gemm_out<<<512, 256, 0, stream>>>(Qp, WoB, bo, out);
}